// Round 16
// baseline (1302.587 us; speedup 1.0000x reference)
//
#include <hip/hip_runtime.h>

// ---- problem constants ----
#define BB 64      // batch
#define TE 40      // encoder steps
#define TD 40      // decoder steps
#define ED 300     // embedding dim
#define EP 320     // padded embedding dim
#define HD 896     // hidden
#define G3 2688    // 3*H
#define VO 30000   // vocab out
#define VP2 30208  // padded vocab (118*256)
#define KZ 1792    // 2*H
#define KT 28      // KZ/64 K-tiles for the 256^2 FC GEMM
#define MR 2560    // T*B rows
#define NBLK 120   // recur role blocks
#define NWB 248    // total blocks (120 roles + 128 FC workers; <=256 CUs)
#define NTN 118    // FC N-tiles per m-group
#define GITEM (NTN + 256)     // items per m-group: 118 tiles + 256 softmax rows
#define NITEM (10 * GITEM)    // unified queue length

// flag regions (flag index; each flag occupies its own 128-B cacheline)
#define FOFF 0     // encoder fwd, 56
#define BOFF 56    // encoder bwd, 56
#define DOFF 112   // decoder GRU, 56
#define AOFF 168   // decoder attn h-slot credit, 64
#define TOFF 232   // transition, 120
#define ZOFF 352   // attn ctx written+drained, 64
#define QOFF 448   // unified work queue counter
#define FWC  456   // fcW conversion completion counter (target 128)
#define MTO  464   // per-m-tile FC completion counters, 10
#define FSTR 32    // ints per flag line (128 B)

typedef __attribute__((ext_vector_type(8))) __bf16 bf16x8;
typedef __attribute__((ext_vector_type(4))) float f32x4;
typedef __attribute__((ext_vector_type(4))) unsigned int u32x4;
typedef __attribute__((ext_vector_type(4))) unsigned short u16x4;

typedef __attribute__((address_space(1))) const void av1c;
typedef __attribute__((address_space(3))) void av3;

__device__ __forceinline__ float sig_(float x)  { return 1.0f / (1.0f + __expf(-x)); }
__device__ __forceinline__ float tanh_(float x) { return 1.0f - 2.0f / (__expf(2.0f * x) + 1.0f); }

// async global->LDS, 16B/lane (linear dest). aux=0 plain; aux=17 = sc0|sc1.
__device__ __forceinline__ void gload_lds16(const __bf16* g, __bf16* l) {
    __builtin_amdgcn_global_load_lds((av1c*)g, (av3*)l, 16, 0, 0);
}
__device__ __forceinline__ void gload_lds16_sc(const __bf16* g, __bf16* l) {
    __builtin_amdgcn_global_load_lds((av1c*)g, (av3*)l, 16, 0, 17);
}

// ---- coherent (cross-XCD) access helpers: sc0 sc1 = L3 coherence point ----
__device__ __forceinline__ bf16x8 ld128_sc(const __bf16* p) {
    bf16x8 r;
    asm volatile("global_load_dwordx4 %0, %1, off sc0 sc1" : "=v"(r) : "v"(p));
    return r;
}
__device__ __forceinline__ f32x4 ldf4_sc(const float* p) {
    f32x4 r;
    asm volatile("global_load_dwordx4 %0, %1, off sc0 sc1" : "=v"(r) : "v"(p));
    return r;
}
__device__ __forceinline__ float ldf_sc(const float* p) {
    float r;
    asm volatile("global_load_dword %0, %1, off sc0 sc1" : "=v"(r) : "v"(p));
    return r;
}
__device__ __forceinline__ void vm_wait0() {
    asm volatile("s_waitcnt vmcnt(0)" ::: "memory");
}
__device__ __forceinline__ void stf_sc(float* p, float v) {
    asm volatile("global_store_dword %0, %1, off sc0 sc1" :: "v"(p), "v"(v) : "memory");
}
__device__ __forceinline__ void sth_sc(__bf16* p, float v) {
    unsigned int u = (unsigned int)__builtin_bit_cast(unsigned short, (__bf16)v);
    asm volatile("global_store_short %0, %1, off sc0 sc1" :: "v"(p), "v"(u) : "memory");
}
__device__ __forceinline__ void st8_sc(__bf16* p, u16x4 v) {
    asm volatile("global_store_dwordx2 %0, %1, off sc0 sc1" :: "v"(p), "v"(v) : "memory");
}
__device__ __forceinline__ void sti_sc(int* p, int v) {
    asm volatile("global_store_dword %0, %1, off sc0 sc1" :: "v"(p), "v"(v) : "memory");
}
// unbounded spin (role chains; co-residency proven structure)
__device__ __forceinline__ void spin_ge(const int* p, int target) {
    int v;
    for (;;) {
        asm volatile("global_load_dword %0, %1, off sc0 sc1\n\ts_waitcnt vmcnt(0)"
                     : "=v"(v) : "v"(p) : "memory");
        if (v >= target) break;
        __builtin_amdgcn_s_sleep(1);
    }
}
// bounded spin (FC/softmax dep edges; expiry -> wrong output, caught by absmax)
__device__ __forceinline__ void spinb(const int* p, int target) {
    for (int it = 0; it < (1 << 20); ++it) {
        int v;
        asm volatile("global_load_dword %0, %1, off sc0 sc1\n\ts_waitcnt vmcnt(0)"
                     : "=v"(v) : "v"(p) : "memory");
        if (v >= target) return;
        __builtin_amdgcn_s_sleep(16);
    }
}

// ---- line-exclusive blocked h layout: element (b, c) -> [(c>>4)*64 + b][c&15]
__device__ __forceinline__ size_t hblk(int b, int c) {
    return ((size_t)(c >> 4) * 64 + b) * 16 + (c & 15);
}

// Stage 48 Whh rows fp32 -> bf16 LDS in fragment order.
__device__ __forceinline__ void stage_w(__bf16* wlds, const float* __restrict__ W, int c0)
{
    const int tid = threadIdx.x;
    for (int ch = tid; ch < 48 * 224; ch += 256) {
        const int lr = ch / 224, c4 = (ch % 224) * 4;
        const int g = lr >> 4, rr = lr & 15;
        const int kk = c4 >> 5, hi = (c4 & 31) >> 3, j = c4 & 7;
        const float4 v = *(const float4*)&W[(size_t)(g * HD + c0 + rr) * HD + c4];
        __bf16* d = &wlds[((g * 28 + kk) * 64 + hi * 16 + rr) * 8 + j];
        d[0] = (__bf16)v.x; d[1] = (__bf16)v.y; d[2] = (__bf16)v.z; d[3] = (__bf16)v.w;
    }
}

struct GiReg { float g0[4], g1[4], g2[4]; };

__device__ __forceinline__ GiReg gi_prefetch(const float* __restrict__ GIt,
                                             int c, int w, int hi)
{
    GiReg r;
#pragma unroll
    for (int rg = 0; rg < 4; ++rg) {
        const float* gp = GIt + (size_t)(16 * w + hi * 4 + rg) * G3 + c;
        r.g0[rg] = gp[0]; r.g1[rg] = gp[HD]; r.g2[rg] = gp[2 * HD];
    }
    return r;
}

// One GRU step (tid<256 only; no internal barriers). Blocked h; Zb sc1.
__device__ __forceinline__ void gru_step(
    const __bf16* __restrict__ hcurB, const float* __restrict__ hcurF,
    const __bf16* __restrict__ wlds, const GiReg& gi,
    float bh0, float bh1, float bh2,
    float* __restrict__ hnF, __bf16* __restrict__ hnB,
    float* __restrict__ yencD, int tt,
    __bf16* __restrict__ zrow,
    int c0, int lane, int w)
{
    const int r16 = lane & 15, hi = lane >> 4;
    const int c = c0 + r16;
    const int colblk = c0 >> 4;
    const int brow = 16 * w;

    bf16x8 afr[28];
    const __bf16* ap = hcurB + ((size_t)(hi >> 1) * 64 + brow + r16) * 16 + (hi & 1) * 8;
#pragma unroll
    for (int kk = 0; kk < 28; ++kk) afr[kk] = ld128_sc(ap + kk * 2048);
    float hp[4];
#pragma unroll
    for (int rg = 0; rg < 4; ++rg)
        hp[rg] = ldf_sc(hcurF + ((size_t)colblk * 64 + brow + hi * 4 + rg) * 16 + r16);
    vm_wait0();
    __builtin_amdgcn_sched_barrier(0);

    f32x4 a0 = {0.f, 0.f, 0.f, 0.f}, a1 = a0, a2 = a0;
#pragma unroll
    for (int kk = 0; kk < 28; ++kk) {
        const bf16x8 b0 = *(const bf16x8*)&wlds[(kk) * 512 + lane * 8];
        const bf16x8 b1 = *(const bf16x8*)&wlds[(28 + kk) * 512 + lane * 8];
        const bf16x8 b2 = *(const bf16x8*)&wlds[(56 + kk) * 512 + lane * 8];
        a0 = __builtin_amdgcn_mfma_f32_16x16x32_bf16(afr[kk], b0, a0, 0, 0, 0);
        a1 = __builtin_amdgcn_mfma_f32_16x16x32_bf16(afr[kk], b1, a1, 0, 0, 0);
        a2 = __builtin_amdgcn_mfma_f32_16x16x32_bf16(afr[kk], b2, a2, 0, 0, 0);
    }

#pragma unroll
    for (int rg = 0; rg < 4; ++rg) {
        const int b = brow + hi * 4 + rg;
        const float rr = sig_(gi.g0[rg] + a0[rg] + bh0);
        const float zz = sig_(gi.g1[rg] + a1[rg] + bh1);
        const float nn = tanh_(gi.g2[rg] + rr * (a2[rg] + bh2));
        const float hnew = (1.0f - zz) * nn + zz * hp[rg];
        const size_t so = ((size_t)colblk * 64 + b) * 16 + r16;
        stf_sc(hnF + so, hnew);
        sth_sc(hnB + so, hnew);
        if (yencD) stf_sc(yencD + (((size_t)colblk * 64 + b) * TE + tt) * 16 + r16, hnew);
        if (zrow)  sth_sc(zrow + (size_t)b * KZ + c, hnew);
    }
}

// attention step, 512-thread uniform barriers.
__device__ __forceinline__ void attn_step512(
    const float* __restrict__ yencL, float* __restrict__ h2s,
    float* __restrict__ scL, float* __restrict__ attwL,
    const float* __restrict__ h2g, int b, __bf16* __restrict__ zr,
    int* __restrict__ myflag, int* __restrict__ zflag, int postval)
{
    const int tid = threadIdx.x, lane = tid & 63, w = tid >> 6;

    float a0 = 0.f, a1 = 0.f;
    if (tid < HD) a0 = ldf_sc(h2g + hblk(b, tid));
    if (tid + 512 < HD) a1 = ldf_sc(h2g + hblk(b, tid + 512));
    vm_wait0();
    __builtin_amdgcn_sched_barrier(0);
    if (tid < HD) h2s[tid] = a0;
    if (tid + 512 < HD) h2s[tid + 512] = a1;
    __syncthreads();
    if (tid == 0) sti_sc(myflag, postval);

    const float2* h22 = (const float2*)h2s;
    for (int t = w; t < TE; t += 8) {
        const float2* y2 = (const float2*)(yencL + t * HD);
        float p = 0.f;
#pragma unroll
        for (int it = 0; it < HD / 128; ++it) {
            const float2 ya = y2[lane + it * 64];
            const float2 hb2 = h22[lane + it * 64];
            p += ya.x * hb2.x + ya.y * hb2.y;
        }
        p += __shfl_down(p, 32); p += __shfl_down(p, 16); p += __shfl_down(p, 8);
        p += __shfl_down(p, 4);  p += __shfl_down(p, 2);  p += __shfl_down(p, 1);
        if (lane == 0) scL[t] = p;
    }
    __syncthreads();

    float m = scL[0];
    for (int t = 1; t < TE; ++t) m = fmaxf(m, scL[t]);
    float s = 0.f;
    for (int t = 0; t < TE; ++t) s += __expf(scL[t] - m);
    const float inv = 1.0f / s;
    if (tid < TE) attwL[tid] = __expf(scL[tid] - m) * inv;
    __syncthreads();

    for (int c = tid; c < HD; c += 512) {
        float acc = 0.f;
#pragma unroll
        for (int t = 0; t < TE; ++t) acc += attwL[t] * yencL[t * HD + c];
        sth_sc(zr + (size_t)b * KZ + HD + c, acc);
    }
    vm_wait0();
    __syncthreads();
    if (tid == 0) sti_sc(zflag, postval);
}

// in-kernel 512-thread row softmax; reads logits via sc1 (L3), writes plain.
__device__ __forceinline__ void softmax512(float* row, float* red, float* red2,
                                           float* __restrict__ orow)
{
    const int tid = threadIdx.x, lane = tid & 63, w = tid >> 6;

    for (int it = 0; it < 3; ++it) {
        f32x4 v[5]; int jj[5]; bool ok[5];
#pragma unroll
        for (int u = 0; u < 5; ++u) {
            jj[u] = it * 2560 + u * 512 + tid;
            ok[u] = jj[u] < VO / 4;
            if (ok[u]) v[u] = ldf4_sc(orow + (size_t)jj[u] * 4);
        }
        vm_wait0();
        __builtin_amdgcn_sched_barrier(0);
#pragma unroll
        for (int u = 0; u < 5; ++u)
            if (ok[u]) *(f32x4*)&row[(size_t)jj[u] * 4] = v[u];
    }
    __syncthreads();

    float m = -1e30f;
    for (int ch = tid; ch < VO / 4; ch += 512) {
        const f32x4 x = *(const f32x4*)&row[ch * 4];
        m = fmaxf(fmaxf(fmaxf(m, x[0]), x[1]), fmaxf(x[2], x[3]));
    }
    m = fmaxf(m, __shfl_down(m, 32)); m = fmaxf(m, __shfl_down(m, 16));
    m = fmaxf(m, __shfl_down(m, 8));  m = fmaxf(m, __shfl_down(m, 4));
    m = fmaxf(m, __shfl_down(m, 2));  m = fmaxf(m, __shfl_down(m, 1));
    if (lane == 0) red[w] = m;
    __syncthreads();
    if (tid == 0) {
        float mm = red[0];
#pragma unroll
        for (int i = 1; i < 8; ++i) mm = fmaxf(mm, red[i]);
        red[0] = mm;
    }
    __syncthreads();
    m = red[0];

    float s = 0.0f;
    for (int v2 = tid; v2 < VO; v2 += 512) {
        const float e = __expf(row[v2] - m);
        row[v2] = e;
        s += e;
    }
    s += __shfl_down(s, 32); s += __shfl_down(s, 16); s += __shfl_down(s, 8);
    s += __shfl_down(s, 4);  s += __shfl_down(s, 2);  s += __shfl_down(s, 1);
    if (lane == 0) red2[w] = s;
    __syncthreads();
    if (tid == 0) {
        float ss = red2[0];
#pragma unroll
        for (int i = 1; i < 8; ++i) ss += red2[i];
        red2[0] = ss;
    }
    __syncthreads();
    s = red2[0];

    const float inv = 1.0f / s;
    for (int ch = tid; ch < VO / 4; ch += 512) {
        f32x4 x = *(const f32x4*)&row[ch * 4];
        x[0] *= inv; x[1] *= inv; x[2] *= inv; x[3] *= inv;
        *(f32x4*)&orow[(size_t)ch * 4] = x;   // plain: kernel-end release flushes
    }
    __syncthreads();
}

// ---------------------------------------------------------------------------
// Persistent kernel: recurrence roles (blocks 0..119) + fcW conversion (worker
// blocks 120..247 during encoder idle) + UNIFIED work queue: per m-group,
// 118 FC tiles then 256 softmax rows (rows gate on that group's MT counter)
// -> softmax overlaps later-group FC instead of running as a serial tail.
// ---------------------------------------------------------------------------
__global__ __launch_bounds__(512, 1) void recur(
    const float* __restrict__ GIf, const float* __restrict__ GIb,
    const float* __restrict__ GId,
    const float* __restrict__ WhhF, const float* __restrict__ WhhB,
    const float* __restrict__ WhhD,
    const float* __restrict__ bhhF, const float* __restrict__ bhhB,
    const float* __restrict__ bhhD,
    float* __restrict__ heF, __bf16* __restrict__ heB,
    float* __restrict__ hdF, __bf16* __restrict__ hdB,
    float* __restrict__ yenc_f, float* __restrict__ yenc_b,
    __bf16* __restrict__ Zb, int* __restrict__ flags,
    const float* __restrict__ fcWsrc, __bf16* __restrict__ fcW,
    float* __restrict__ outC, const float* __restrict__ fcb)
{
    __shared__ __align__(16) char smem[147456];
    __bf16* wlds  = (__bf16*)smem;
    float*  yencL = (float*)smem;
    float*  h2s   = (float*)(smem + 143360);
    float*  scL   = (float*)(smem + 146944);
    float*  attwL = (float*)(smem + 147136);
    float*  redA  = (float*)(smem + 131072);
    float*  redB  = (float*)(smem + 131136);
    volatile int* shtile = (volatile int*)(smem + 147400);

    const int gid = blockIdx.x;
    const int tid = threadIdx.x;
    const int lane = tid & 63, w = tid >> 6;
    const int r16 = lane & 15, hi = lane >> 4;
    const size_t S = (size_t)BB * HD;

    if (gid < NBLK) {
        float bb0 = 0.f, bb1 = 0.f, bb2 = 0.f;
        GiReg gi;

        // ================= encoder =================
        if (gid < 112) {
            const int dir = (gid >= 56) ? 1 : 0;
            const int gloc = dir ? gid - 56 : gid;
            const int c0e = gloc * 16;
            const float* GIe  = dir ? GIb : GIf;
            const float* bhhE = dir ? bhhB : bhhF;
            float* yencD = dir ? yenc_b : yenc_f;
            const int foff = dir ? BOFF : FOFF;
            const int ce = c0e + r16;

            stage_w(wlds, dir ? WhhB : WhhF, c0e);
            if (tid < 256) {
                bb0 = bhhE[ce]; bb1 = bhhE[HD + ce]; bb2 = bhhE[2 * HD + ce];
                gi = gi_prefetch(GIe + (size_t)(dir ? TE - 1 : 0) * BB * G3, ce, w, hi);
            }
            __syncthreads();

            for (int t = 0; t < TE; ++t) {
                if (t > 0) {
                    if (tid < 56) spin_ge(flags + (foff + tid) * FSTR, t);
                    __syncthreads();
                }
                const int tt = dir ? (TE - 1 - t) : t;
                if (tid < 256)
                    gru_step(heB + (size_t)(dir * 2 + (t & 1)) * S,
                             heF + (size_t)(dir * 2 + (t & 1)) * S,
                             wlds, gi, bb0, bb1, bb2,
                             heF + (size_t)(dir * 2 + ((t + 1) & 1)) * S,
                             heB + (size_t)(dir * 2 + ((t + 1) & 1)) * S,
                             yencD, tt, nullptr, c0e, lane, w);
                vm_wait0();
                __syncthreads();
                if (tid == 0) sti_sc(flags + (foff + gloc) * FSTR, t + 1);
                if (t + 1 < TE && tid < 256) {
                    const int ttn = dir ? (TE - 2 - t) : (t + 1);
                    gi = gi_prefetch(GIe + (size_t)ttn * BB * G3, ce, w, hi);
                }
            }
        }

        // ================= transition =================
        if (tid < 112) spin_ge(flags + tid * FSTR, TE);
        __syncthreads();

        {
            const int i0 = gid * 256 + tid;
            const int i1 = i0 + NBLK * 256;
            const bool has0 = (i0 < BB * HD);
            const bool has1 = (i1 < BB * HD);
            const float f0 = has0 ? ldf_sc(&heF[0 * S + i0]) : 0.f;
            const float b0 = has0 ? ldf_sc(&heF[2 * S + i0]) : 0.f;
            const float f1 = has1 ? ldf_sc(&heF[0 * S + i1]) : 0.f;
            const float b1 = has1 ? ldf_sc(&heF[2 * S + i1]) : 0.f;
            vm_wait0();
            __builtin_amdgcn_sched_barrier(0);
            if (has0) { const float v0 = f0 + b0; stf_sc(&hdF[i0], v0); sth_sc(&hdB[i0], v0); }
            if (has1) { const float v1 = f1 + b1; stf_sc(&hdF[i1], v1); sth_sc(&hdB[i1], v1); }
        }
        if (gid < 56) {
            stage_w(wlds, WhhD, gid * 16);
            if (tid < 256) {
                const int cd = gid * 16 + r16;
                bb0 = bhhD[cd]; bb1 = bhhD[HD + cd]; bb2 = bhhD[2 * HD + cd];
                gi = gi_prefetch(GId, cd, w, hi);
            }
        }
        vm_wait0();
        __syncthreads();
        if (tid == 0) sti_sc(flags + (TOFF + gid) * FSTR, 1);
        if (tid < 120) spin_ge(flags + (TOFF + tid) * FSTR, 1);
        __syncthreads();

        // ================= decoder =================
        if (gid < 56) {
            for (int p = 0; p < TD; ++p) {
                if (p > 0 && tid < 56) spin_ge(flags + (DOFF + tid) * FSTR, p);
                if (p >= 4 && tid >= 64 && tid < 128)
                    spin_ge(flags + (AOFF + tid - 64) * FSTR, p - 3);
                __syncthreads();
                if (tid < 256)
                    gru_step(hdB + (size_t)(p & 3) * S, hdF + (size_t)(p & 3) * S,
                             wlds, gi, bb0, bb1, bb2,
                             hdF + (size_t)((p + 1) & 3) * S, hdB + (size_t)((p + 1) & 3) * S,
                             nullptr, 0, Zb + (size_t)p * BB * KZ, gid * 16, lane, w);
                vm_wait0();
                __syncthreads();
                if (tid == 0) sti_sc(flags + (DOFF + gid) * FSTR, p + 1);
                if (p + 1 < TD && tid < 256)
                    gi = gi_prefetch(GId + (size_t)(p + 1) * BB * G3, gid * 16 + r16, w, hi);
            }
        } else {
            const int b = gid - 56;
            const float* sf = yenc_f;
            const float* sb = yenc_b;
            for (int it = 0; it < 4; ++it) {
                f32x4 a_[5], b_[5];
                int tt_[5], gg_[5], cc_[5]; bool ok[5];
#pragma unroll
                for (int u = 0; u < 5; ++u) {
                    const int j = it * 2560 + u * 512 + tid;
                    ok[u] = (j < 8960);
                    if (ok[u]) {
                        gg_[u] = j / 160;
                        const int rem = j - gg_[u] * 160;
                        tt_[u] = rem >> 2;
                        cc_[u] = (rem & 3) * 4;
                        const size_t sa = (((size_t)gg_[u] * 64 + b) * TE + tt_[u]) * 16 + cc_[u];
                        a_[u] = ldf4_sc(sf + sa);
                        b_[u] = ldf4_sc(sb + sa);
                    }
                }
                vm_wait0();
                __builtin_amdgcn_sched_barrier(0);
#pragma unroll
                for (int u = 0; u < 5; ++u)
                    if (ok[u])
                        *(f32x4*)&yencL[(size_t)tt_[u] * HD + gg_[u] * 16 + cc_[u]] = a_[u] + b_[u];
            }
            __syncthreads();
            for (int s = 0; s < TD; ++s) {
                if (tid < 56) spin_ge(flags + (DOFF + tid) * FSTR, s + 1);
                __syncthreads();
                attn_step512(yencL, h2s, scL, attwL, hdF + (size_t)((s + 1) & 3) * S,
                             b, Zb + (size_t)s * BB * KZ,
                             flags + (AOFF + b) * FSTR, flags + (ZOFF + b) * FSTR, s + 1);
            }
        }
    } else {
        // ============ worker blocks: convert fcW fp32->bf16 (sc1) ============
        const int slice = gid - NBLK;                    // 0..127
        const size_t base = (size_t)slice * 236 * KZ;    // 236 rows per slice
        const int nf4 = 236 * KZ / 4;
        for (int i = tid; i < nf4; i += 512) {
            const size_t e0 = base + (size_t)i * 4;
            const int r = (int)(e0 / KZ);
            u16x4 o;
            if (r < VO) {
                const float4 x = *(const float4*)&fcWsrc[e0];
                o.x = __builtin_bit_cast(unsigned short, (__bf16)x.x);
                o.y = __builtin_bit_cast(unsigned short, (__bf16)x.y);
                o.z = __builtin_bit_cast(unsigned short, (__bf16)x.z);
                o.w = __builtin_bit_cast(unsigned short, (__bf16)x.w);
            } else {
                o.x = 0; o.y = 0; o.z = 0; o.w = 0;
            }
            st8_sc(&fcW[e0], o);
        }
        vm_wait0();
        __syncthreads();
        if (tid == 0)
            __hip_atomic_fetch_add(flags + FWC * FSTR, 1, __ATOMIC_RELAXED,
                                   __HIP_MEMORY_SCOPE_AGENT);
    }

    // ============ unified FC + softmax queue (all blocks) ============
    {
        __bf16* lds = (__bf16*)smem;
        const int wave = tid >> 6;
        const int wm = wave >> 2, wn = wave & 3;
        int* qcnt = flags + QOFF * FSTR;

        if (tid == 0) spinb(flags + FWC * FSTR, 128);   // fcW conversion done
        __syncthreads();

        const int srow0 = wave * 8 + (lane >> 3);
        const int scol  = ((lane & 7) ^ (lane >> 3)) * 8;
        const int cbx0 = ((hi * 16) ^ ((r16 & 7) << 4)) >> 1;
        const int cbx1 = ((64 + hi * 16) ^ ((r16 & 7) << 4)) >> 1;

        for (;;) {
            if (tid == 0) {
                const int tl = __hip_atomic_fetch_add(qcnt, 1, __ATOMIC_RELAXED,
                                                      __HIP_MEMORY_SCOPE_AGENT);
                *shtile = tl;
            }
            __syncthreads();
            const int item = *shtile;
            if (item >= NITEM) break;
            const int mt = item / GITEM;
            const int sub = item - mt * GITEM;

            if (sub >= NTN) {
                // -------- softmax row item: gate on group's FC completion ----
                const int r = sub - NTN;
                if (tid == 0) spinb(flags + (MTO + mt) * FSTR, NTN);
                __syncthreads();
                const int t = 4 * mt + (r >> 6), b = r & 63;
                softmax512((float*)smem, redA, redB, outC + (size_t)(b * TD + t) * VO);
                continue;
            }

            // -------- FC tile item --------
            const int nt = sub;
            const int need = 4 * mt + 4;
            if (tid < 56) spinb(flags + (DOFF + tid) * FSTR, need);
            if (tid >= 64 && tid < 128) spinb(flags + (ZOFF + tid - 64) * FSTR, need);
            __syncthreads();

            const long tileM = (long)mt * 256;
            const long tileN = (long)nt * 256;
            const __bf16* gAh[2] = { Zb + (size_t)tileM * KZ, Zb + (size_t)(tileM + 128) * KZ };
            const __bf16* gBh[2] = { fcW + (size_t)tileN * KZ, fcW + (size_t)(tileN + 128) * KZ };
            auto Abase = [](int buf, int h) { return (buf * 2 + h) * 8192; };
            auto Bbase = [](int buf, int h) { return 32768 + (buf * 2 + h) * 8192; };
            auto stageA = [&](const __bf16* gph, int kt, int lbase) {
                const __bf16* g0 = gph + (size_t)srow0 * KZ + kt * 64 + scol;
                gload_lds16_sc(g0, &lds[lbase + wave * 512]);
                gload_lds16_sc(g0 + (size_t)64 * KZ, &lds[lbase + (8 + wave) * 512]);
            };
            auto stageB = [&](const __bf16* gph, int kt, int lbase) {
                const __bf16* g0 = gph + (size_t)srow0 * KZ + kt * 64 + scol;
                gload_lds16(g0, &lds[lbase + wave * 512]);
                gload_lds16(g0 + (size_t)64 * KZ, &lds[lbase + (8 + wave) * 512]);
            };

            f32x4 acc[8][4];
            const f32x4 zero = {0.f, 0.f, 0.f, 0.f};
#pragma unroll
            for (int m = 0; m < 8; ++m)
#pragma unroll
                for (int n = 0; n < 4; ++n) acc[m][n] = zero;

            stageA(gAh[0], 0, Abase(0, 0));
            stageA(gAh[1], 0, Abase(0, 1));
            stageB(gBh[0], 0, Bbase(0, 0));
            stageB(gBh[1], 0, Bbase(0, 1));
            stageB(gBh[0], 1, Bbase(1, 0));
            stageB(gBh[1], 1, Bbase(1, 1));
            asm volatile("s_waitcnt vmcnt(4)" ::: "memory");
            __builtin_amdgcn_s_barrier();

            for (int kt = 0; kt < KT; ++kt) {
                const int buf = kt & 1;
                const int kn1 = (kt + 1 < KT) ? kt + 1 : 0;
                const int kn2 = (kt + 2 < KT) ? kt + 2 : 0;
                const int Ab = Abase(buf, wm);
                const int Bb = Bbase(buf, wn >> 1);
                bf16x8 bfr[4][2];
#pragma unroll
                for (int q = 0; q < 4; ++q) {
                    if (q == 0) {
#pragma unroll
                        for (int n = 0; n < 4; ++n) {
                            const int rowB = (wn & 1) * 64 + n * 16 + r16;
                            bfr[n][0] = *(const bf16x8*)&lds[Bb + rowB * 64 + cbx0];
                            bfr[n][1] = *(const bf16x8*)&lds[Bb + rowB * 64 + cbx1];
                        }
                    }
                    bf16x8 af[2][2];
#pragma unroll
                    for (int mm = 0; mm < 2; ++mm) {
                        const int rowA = (q * 2 + mm) * 16 + r16;
                        af[mm][0] = *(const bf16x8*)&lds[Ab + rowA * 64 + cbx0];
                        af[mm][1] = *(const bf16x8*)&lds[Ab + rowA * 64 + cbx1];
                    }
                    if (q == 0)      stageA(gAh[0], kn1, Abase(buf ^ 1, 0));
                    else if (q == 1) stageA(gAh[1], kn1, Abase(buf ^ 1, 1));
                    else if (q == 2) stageB(gBh[0], kn2, Bbase(buf, 0));
                    else {
                        stageB(gBh[1], kn2, Bbase(buf, 1));
                        asm volatile("s_waitcnt vmcnt(4)" ::: "memory");
                    }
                    __builtin_amdgcn_s_barrier();
                    asm volatile("s_waitcnt lgkmcnt(0)" ::: "memory");
                    __builtin_amdgcn_sched_barrier(0);
                    __builtin_amdgcn_s_setprio(1);
#pragma unroll
                    for (int mm = 0; mm < 2; ++mm)
#pragma unroll
                        for (int n = 0; n < 4; ++n) {
                            acc[q * 2 + mm][n] = __builtin_amdgcn_mfma_f32_16x16x32_bf16(
                                af[mm][0], bfr[n][0], acc[q * 2 + mm][n], 0, 0, 0);
                            acc[q * 2 + mm][n] = __builtin_amdgcn_mfma_f32_16x16x32_bf16(
                                af[mm][1], bfr[n][1], acc[q * 2 + mm][n], 0, 0, 0);
                        }
                    __builtin_amdgcn_s_setprio(0);
                    __builtin_amdgcn_sched_barrier(0);
                    __builtin_amdgcn_s_barrier();
                }
            }
            asm volatile("s_waitcnt vmcnt(0)" ::: "memory");

            // epilogue: sc1 stores (read back in-kernel by softmax), then MT inc
#pragma unroll
            for (int m = 0; m < 8; ++m) {
#pragma unroll
                for (int n = 0; n < 4; ++n) {
                    const long gcol = tileN + wn * 64 + n * 16 + r16;
                    if (gcol >= VO) continue;
                    const float bv = fcb[gcol];
#pragma unroll
                    for (int rr = 0; rr < 4; ++rr) {
                        const long grow = tileM + wm * 128 + m * 16 + hi * 4 + rr;
                        const long t = grow >> 6, b = grow & 63;
                        stf_sc(&outC[(b * TD + t) * VO + gcol], acc[m][n][rr] + bv);
                    }
                }
            }
            vm_wait0();
            __syncthreads();
            if (tid == 0)
                __hip_atomic_fetch_add(flags + (MTO + mt) * FSTR, 1, __ATOMIC_RELAXED,
                                       __HIP_MEMORY_SCOPE_AGENT);
            __syncthreads();
        }
    }
}

// ---------------------------------------------------------------------------
// 128^2 T3+T4 GEMM (proven): input-side GEMMs. fp32 C.
// ---------------------------------------------------------------------------
__global__ __launch_bounds__(256) void gemm_bt(
    const __bf16* __restrict__ A0, const __bf16* __restrict__ B0,
    float* __restrict__ C0, const float* __restrict__ bias0,
    const __bf16* __restrict__ A1, const __bf16* __restrict__ B1,
    float* __restrict__ C1, const float* __restrict__ bias1,
    int M, int N, int K)
{
    constexpr int BM = 128, BN = 128, BK = 32;
    constexpr int FM = 4, FN = 4;

    const __bf16* A = A0; const __bf16* Bp = B0;
    float* C = C0; const float* bias = bias0;
    if (blockIdx.z == 1) { A = A1; Bp = B1; C = C1; bias = bias1; }

    __shared__ __bf16 Ash[2][BM * BK];
    __shared__ __bf16 Bsh[2][BN * BK];

    const int tid  = threadIdx.x;
    const int lane = tid & 63;
    const int wave = tid >> 6;
    const int wr = wave >> 1, wc = wave & 1;

    const int nwg = gridDim.x * gridDim.y;
    const int orig = blockIdx.y * gridDim.x + blockIdx.x;
    const int q = nwg >> 3, r = nwg & 7;
    const int xcd = orig & 7, idx = orig >> 3;
    const int wg = (xcd < r ? xcd * (q + 1) : r * (q + 1) + (xcd - r) * q) + idx;
    const int mtiles = gridDim.y;
    const long tileM = (long)(wg % mtiles) * BM;
    const long tileN = (long)(wg / mtiles) * BN;

    const int r16 = lane & 15;
    const int hi  = lane >> 4;

    f32x4 acc[FM][FN];
    const f32x4 zero = {0.f, 0.f, 0.f, 0.f};
#pragma unroll
    for (int m = 0; m < FM; ++m)
#pragma unroll
        for (int n = 0; n < FN; ++n) acc[m][n] = zero;

    const int srow = wave * 32 + (lane >> 2);
    const int schunk = (lane & 3) * 8;
    const __bf16* gA = A + (size_t)(tileM + srow) * K + schunk;
    const __bf16* gB = Bp + (size_t)(tileN + srow) * K + schunk;
    const size_t kstep16 = (size_t)16 * K;
    const int lofs = (wave * 32) * BK;

#define STAGE_T(k0_, sel_)                                            \
    do {                                                              \
        gload_lds16(gA + (k0_), &Ash[sel_][lofs]);                    \
        gload_lds16(gA + (k0_) + kstep16, &Ash[sel_][lofs + 16 * BK]);\
        gload_lds16(gB + (k0_), &Bsh[sel_][lofs]);                    \
        gload_lds16(gB + (k0_) + kstep16, &Bsh[sel_][lofs + 16 * BK]);\
    } while (0)

    STAGE_T(0, 0);
    int cur = 0;
    for (int k0 = BK; k0 < K; k0 += BK) {
        STAGE_T(k0, cur ^ 1);
        asm volatile("s_waitcnt vmcnt(4)" ::: "memory");
        __builtin_amdgcn_s_barrier();
        __builtin_amdgcn_sched_barrier(0);

        bf16x8 af[FM], bfr[FN];
#pragma unroll
        for (int m = 0; m < FM; ++m)
            af[m] = *(const bf16x8*)&Ash[cur][(wr * 64 + m * 16 + r16) * BK + hi * 8];
#pragma unroll
        for (int n = 0; n < FN; ++n)
            bfr[n] = *(const bf16x8*)&Bsh[cur][(wc * 64 + n * 16 + r16) * BK + hi * 8];
#pragma unroll
        for (int m = 0; m < FM; ++m)
#pragma unroll
            for (int n = 0; n < FN; ++n)
                acc[m][n] = __builtin_amdgcn_mfma_f32_16x16x32_bf16(af[m], bfr[n], acc[m][n], 0, 0, 0);

        __builtin_amdgcn_sched_barrier(0);
        __builtin_amdgcn_s_barrier();
        __builtin_amdgcn_sched_barrier(0);
        cur ^= 1;
    }
    asm volatile("s_waitcnt vmcnt(0)" ::: "memory");
    __builtin_amdgcn_s_barrier();
    __builtin_amdgcn_sched_barrier(0);
    {
        bf16x8 af[FM], bfr[FN];
#pragma unroll
        for (int m = 0; m < FM; ++m)
            af[m] = *(const bf16x8*)&Ash[cur][(wr * 64 + m * 16 + r16) * BK + hi * 8];
#pragma unroll
        for (int n = 0; n < FN; ++n)
            bfr[n] = *(const bf16x8*)&Bsh[cur][(wc * 64 + n * 16 + r16) * BK + hi * 8];
#pragma unroll
        for (int m = 0; m < FM; ++m)
#pragma unroll
            for (int n = 0; n < FN; ++n)
                acc[m][n] = __builtin_amdgcn_mfma_f32_16x16x32_bf16(af[m], bfr[n], acc[m][n], 0, 0, 0);
    }
#undef STAGE_T

#pragma unroll
    for (int m = 0; m < FM; ++m) {
#pragma unroll
        for (int n = 0; n < FN; ++n) {
            const long gcol = tileN + wc * 64 + n * 16 + r16;
            const float bv = bias ? bias[gcol] : 0.0f;
#pragma unroll
            for (int rr = 0; rr < 4; ++rr) {
                const long grow = tileM + wr * 64 + m * 16 + hi * 4 + rr;
                C[grow * N + gcol] = acc[m][n][rr] + bv;
            }
        }
    }
}

// fp32 -> bf16 convert with row/col zero-padding (small Wih matrices)
__global__ __launch_bounds__(256) void conv_pad(const float* __restrict__ src,
                                                __bf16* __restrict__ dst,
                                                int Rout, int Rin, int Kout, int Kin)
{
    size_t i = (size_t)blockIdx.x * 256 + threadIdx.x;
    const size_t total = (size_t)Rout * Kout;
    const size_t stride = (size_t)gridDim.x * 256;
    for (; i < total; i += stride) {
        int k = (int)(i % Kout);
        int r = (int)(i / Kout);
        float v = (r < Rin && k < Kin) ? src[(size_t)r * Kin + k] : 0.0f;
        dst[i] = (__bf16)v;
    }
}

// gather token embeddings into padded bf16 matrix X[(t*B+b)][EP]
__global__ __launch_bounds__(256) void gather_embed(const int* __restrict__ tok,
                                                    const float* __restrict__ emb,
                                                    __bf16* __restrict__ X)
{
    int i = blockIdx.x * 256 + threadIdx.x;
    const int total = TE * BB * EP;
    for (; i < total; i += gridDim.x * 256) {
        int e = i % EP;
        int row = i / EP;
        int t = row >> 6, b = row & 63;
        float v = 0.0f;
        if (e < ED) v = emb[(size_t)tok[b * TE + t] * ED + e];
        X[i] = (__bf16)v;
    }
}

extern "C" void kernel_launch(void* const* d_in, const int* in_sizes, int n_in,
                              void* d_out, int out_size, void* d_ws, size_t ws_size,
                              hipStream_t stream)
{
    if (n_in < 18) return;
    const int*   x_enc   = (const int*)d_in[0];
    const int*   x_dec   = (const int*)d_in[1];
    const float* emb_enc = (const float*)d_in[2];
    const float* Wih_f   = (const float*)d_in[3];
    const float* Whh_f   = (const float*)d_in[4];
    const float* bih_f   = (const float*)d_in[5];
    const float* bhh_f   = (const float*)d_in[6];
    const float* Wih_b   = (const float*)d_in[7];
    const float* Whh_b   = (const float*)d_in[8];
    const float* bih_b   = (const float*)d_in[9];
    const float* bhh_b   = (const float*)d_in[10];
    const float* emb_dec = (const float*)d_in[11];
    const float* Wih_d   = (const float*)d_in[12];
    const float* Whh_d   = (const float*)d_in[13];
    const float* bih_d   = (const float*)d_in[14];
    const float* bhh_d   = (const float*)d_in[15];
    const float* fc_W    = (const float*)d_in[16];
    const float* fc_b    = (const float*)d_in[17];
    float* out = (float*)d_out;

    size_t off = 0;
    auto alloc = [&](size_t bytes) -> void* {
        void* p = (char*)d_ws + off;
        off = (off + bytes + 255) & ~(size_t)255;
        return p;
    };
    __bf16* fcWb   = (__bf16*)alloc((size_t)VP2 * KZ * 2);
    __bf16* WihFb  = (__bf16*)alloc((size_t)G3 * EP * 2);
    __bf16* WihBb  = (__bf16*)alloc((size_t)G3 * EP * 2);
    __bf16* WihDb  = (__bf16*)alloc((size_t)G3 * EP * 2);
    __bf16* Xe     = (__bf16*)alloc((size_t)MR * EP * 2);
    __bf16* Xd     = (__bf16*)alloc((size_t)MR * EP * 2);
    float*  GIf    = (float*)alloc((size_t)MR * G3 * 4);
    float*  GIb    = (float*)alloc((size_t)MR * G3 * 4);
    float*  GId    = (float*)alloc((size_t)MR * G3 * 4);
    __bf16* Zb     = (__bf16*)alloc((size_t)MR * KZ * 2);
    float*  yenc_f = (float*)alloc((size_t)BB * TE * HD * 4);
    float*  yenc_b = (float*)alloc((size_t)BB * TE * HD * 4);
    float*  hdF    = (float*)alloc((size_t)4 * BB * HD * 4);
    __bf16* hdB    = (__bf16*)alloc((size_t)4 * BB * HD * 2);
    char* zero_start = (char*)d_ws + off;
    float*  heF    = (float*)alloc((size_t)4 * BB * HD * 4);
    __bf16* heB    = (__bf16*)alloc((size_t)4 * BB * HD * 2);
    int*    flags  = (int*)alloc(512 * FSTR * 4);
    size_t zero_bytes = (size_t)(((char*)d_ws + off) - zero_start);
    if (off > ws_size) return;   // ~230 MB required; fail visibly (zero output)

    // ---- init + small weight conversion + embedding gather ----
    hipMemsetAsync(zero_start, 0, zero_bytes, stream);
    conv_pad<<<3360, 256, 0, stream>>>(Wih_f, WihFb, G3, G3, EP, ED);
    conv_pad<<<3360, 256, 0, stream>>>(Wih_b, WihBb, G3, G3, EP, ED);
    conv_pad<<<3360, 256, 0, stream>>>(Wih_d, WihDb, G3, G3, EP, ED);
    gather_embed<<<3200, 256, 0, stream>>>(x_enc, emb_enc, Xe);
    gather_embed<<<3200, 256, 0, stream>>>(x_dec, emb_dec, Xd);

    // ---- batched input-side GEMMs: GI = X @ Wih^T + bih ----
    gemm_bt<<<dim3(G3 / 128, MR / 128, 2), 256, 0, stream>>>(
        Xe, WihFb, GIf, bih_f, Xe, WihBb, GIb, bih_b, MR, G3, EP);
    gemm_bt<<<dim3(G3 / 128, MR / 128, 1), 256, 0, stream>>>(
        Xd, WihDb, GId, bih_d, nullptr, nullptr, nullptr, nullptr, MR, G3, EP);

    // ---- persistent: recurrence + fcW conversion + FC + softmax (one kernel) --
    recur<<<NWB, 512, 0, stream>>>(GIf, GIb, GId, Whh_f, Whh_b, Whh_d,
                                   bhh_f, bhh_b, bhh_d,
                                   heF, heB, hdF, hdB, yenc_f, yenc_b, Zb, flags,
                                   fc_W, fcWb, out, fc_b);
}

// Round 17
// 1004.528 us; speedup vs baseline: 1.2967x; 1.2967x over previous
//
#include <hip/hip_runtime.h>

// ---- problem constants ----
#define BB 64      // batch
#define TE 40      // encoder steps
#define TD 40      // decoder steps
#define ED 300     // embedding dim
#define EP 320     // padded embedding dim
#define HD 896     // hidden
#define G3 2688    // 3*H
#define VO 30000   // vocab out
#define VP2 30208  // padded vocab (118*256)
#define KZ 1792    // 2*H
#define KT 28      // KZ/64 K-tiles for the 256^2 FC GEMM
#define MR 2560    // T*B rows
#define NBLK 120   // recur role blocks
#define NWB 248    // total blocks (120 roles + 128 FC workers; <=256 CUs)
#define NTN 118    // FC N-tiles per m-group
#define NITEM 3740 // unified queue: 10*118 tiles + 10*256 rows

// flag regions (flag index; each flag occupies its own 128-B cacheline)
#define FOFF 0     // encoder fwd, 56
#define BOFF 56    // encoder bwd, 56
#define DOFF 112   // decoder GRU, 56
#define AOFF 168   // decoder attn h-slot credit, 64
#define TOFF 232   // transition, 120
#define ZOFF 352   // attn ctx written+drained, 64
#define QOFF 448   // unified work queue counter
#define FWC  456   // fcW conversion completion counter (target 128)
#define MTO  464   // per-m-tile FC completion counters, 10
#define FSTR 32    // ints per flag line (128 B)

typedef __attribute__((ext_vector_type(8))) __bf16 bf16x8;
typedef __attribute__((ext_vector_type(4))) float f32x4;
typedef __attribute__((ext_vector_type(4))) unsigned int u32x4;
typedef __attribute__((ext_vector_type(4))) unsigned short u16x4;

typedef __attribute__((address_space(1))) const void av1c;
typedef __attribute__((address_space(3))) void av3;

__device__ __forceinline__ float sig_(float x)  { return 1.0f / (1.0f + __expf(-x)); }
__device__ __forceinline__ float tanh_(float x) { return 1.0f - 2.0f / (__expf(2.0f * x) + 1.0f); }

// async global->LDS, 16B/lane (linear dest). aux=0 plain; aux=17 = sc0|sc1.
__device__ __forceinline__ void gload_lds16(const __bf16* g, __bf16* l) {
    __builtin_amdgcn_global_load_lds((av1c*)g, (av3*)l, 16, 0, 0);
}
__device__ __forceinline__ void gload_lds16_sc(const __bf16* g, __bf16* l) {
    __builtin_amdgcn_global_load_lds((av1c*)g, (av3*)l, 16, 0, 17);
}

// ---- coherent (cross-XCD) access helpers: sc0 sc1 = L3 coherence point ----
__device__ __forceinline__ bf16x8 ld128_sc(const __bf16* p) {
    bf16x8 r;
    asm volatile("global_load_dwordx4 %0, %1, off sc0 sc1" : "=v"(r) : "v"(p));
    return r;
}
__device__ __forceinline__ f32x4 ldf4_sc(const float* p) {
    f32x4 r;
    asm volatile("global_load_dwordx4 %0, %1, off sc0 sc1" : "=v"(r) : "v"(p));
    return r;
}
__device__ __forceinline__ float ldf_sc(const float* p) {
    float r;
    asm volatile("global_load_dword %0, %1, off sc0 sc1" : "=v"(r) : "v"(p));
    return r;
}
__device__ __forceinline__ void vm_wait0() {
    asm volatile("s_waitcnt vmcnt(0)" ::: "memory");
}
__device__ __forceinline__ void stf_sc(float* p, float v) {
    asm volatile("global_store_dword %0, %1, off sc0 sc1" :: "v"(p), "v"(v) : "memory");
}
__device__ __forceinline__ void sth_sc(__bf16* p, float v) {
    unsigned int u = (unsigned int)__builtin_bit_cast(unsigned short, (__bf16)v);
    asm volatile("global_store_short %0, %1, off sc0 sc1" :: "v"(p), "v"(u) : "memory");
}
__device__ __forceinline__ void st8_sc(__bf16* p, u16x4 v) {
    asm volatile("global_store_dwordx2 %0, %1, off sc0 sc1" :: "v"(p), "v"(v) : "memory");
}
__device__ __forceinline__ void sti_sc(int* p, int v) {
    asm volatile("global_store_dword %0, %1, off sc0 sc1" :: "v"(p), "v"(v) : "memory");
}
// unbounded spin (role chains; co-residency proven structure)
__device__ __forceinline__ void spin_ge(const int* p, int target) {
    int v;
    for (;;) {
        asm volatile("global_load_dword %0, %1, off sc0 sc1\n\ts_waitcnt vmcnt(0)"
                     : "=v"(v) : "v"(p) : "memory");
        if (v >= target) break;
        __builtin_amdgcn_s_sleep(1);
    }
}
// bounded spin (FC/softmax dep edges; expiry -> wrong output, caught by absmax)
__device__ __forceinline__ void spinb(const int* p, int target) {
    for (int it = 0; it < (1 << 20); ++it) {
        int v;
        asm volatile("global_load_dword %0, %1, off sc0 sc1\n\ts_waitcnt vmcnt(0)"
                     : "=v"(v) : "v"(p) : "memory");
        if (v >= target) return;
        __builtin_amdgcn_s_sleep(16);
    }
}

// ---- line-exclusive blocked h layout: element (b, c) -> [(c>>4)*64 + b][c&15]
__device__ __forceinline__ size_t hblk(int b, int c) {
    return ((size_t)(c >> 4) * 64 + b) * 16 + (c & 15);
}

// Stage 48 Whh rows fp32 -> bf16 LDS in fragment order.
__device__ __forceinline__ void stage_w(__bf16* wlds, const float* __restrict__ W, int c0)
{
    const int tid = threadIdx.x;
    for (int ch = tid; ch < 48 * 224; ch += 256) {
        const int lr = ch / 224, c4 = (ch % 224) * 4;
        const int g = lr >> 4, rr = lr & 15;
        const int kk = c4 >> 5, hi = (c4 & 31) >> 3, j = c4 & 7;
        const float4 v = *(const float4*)&W[(size_t)(g * HD + c0 + rr) * HD + c4];
        __bf16* d = &wlds[((g * 28 + kk) * 64 + hi * 16 + rr) * 8 + j];
        d[0] = (__bf16)v.x; d[1] = (__bf16)v.y; d[2] = (__bf16)v.z; d[3] = (__bf16)v.w;
    }
}

struct GiReg { float g0[4], g1[4], g2[4]; };

__device__ __forceinline__ GiReg gi_prefetch(const float* __restrict__ GIt,
                                             int c, int w, int hi)
{
    GiReg r;
#pragma unroll
    for (int rg = 0; rg < 4; ++rg) {
        const float* gp = GIt + (size_t)(16 * w + hi * 4 + rg) * G3 + c;
        r.g0[rg] = gp[0]; r.g1[rg] = gp[HD]; r.g2[rg] = gp[2 * HD];
    }
    return r;
}

// One GRU step (tid<256 only; no internal barriers). Blocked h; Zb sc1.
__device__ __forceinline__ void gru_step(
    const __bf16* __restrict__ hcurB, const float* __restrict__ hcurF,
    const __bf16* __restrict__ wlds, const GiReg& gi,
    float bh0, float bh1, float bh2,
    float* __restrict__ hnF, __bf16* __restrict__ hnB,
    float* __restrict__ yencD, int tt,
    __bf16* __restrict__ zrow,
    int c0, int lane, int w)
{
    const int r16 = lane & 15, hi = lane >> 4;
    const int c = c0 + r16;
    const int colblk = c0 >> 4;
    const int brow = 16 * w;

    bf16x8 afr[28];
    const __bf16* ap = hcurB + ((size_t)(hi >> 1) * 64 + brow + r16) * 16 + (hi & 1) * 8;
#pragma unroll
    for (int kk = 0; kk < 28; ++kk) afr[kk] = ld128_sc(ap + kk * 2048);
    float hp[4];
#pragma unroll
    for (int rg = 0; rg < 4; ++rg)
        hp[rg] = ldf_sc(hcurF + ((size_t)colblk * 64 + brow + hi * 4 + rg) * 16 + r16);
    vm_wait0();
    __builtin_amdgcn_sched_barrier(0);

    f32x4 a0 = {0.f, 0.f, 0.f, 0.f}, a1 = a0, a2 = a0;
#pragma unroll
    for (int kk = 0; kk < 28; ++kk) {
        const bf16x8 b0 = *(const bf16x8*)&wlds[(kk) * 512 + lane * 8];
        const bf16x8 b1 = *(const bf16x8*)&wlds[(28 + kk) * 512 + lane * 8];
        const bf16x8 b2 = *(const bf16x8*)&wlds[(56 + kk) * 512 + lane * 8];
        a0 = __builtin_amdgcn_mfma_f32_16x16x32_bf16(afr[kk], b0, a0, 0, 0, 0);
        a1 = __builtin_amdgcn_mfma_f32_16x16x32_bf16(afr[kk], b1, a1, 0, 0, 0);
        a2 = __builtin_amdgcn_mfma_f32_16x16x32_bf16(afr[kk], b2, a2, 0, 0, 0);
    }

#pragma unroll
    for (int rg = 0; rg < 4; ++rg) {
        const int b = brow + hi * 4 + rg;
        const float rr = sig_(gi.g0[rg] + a0[rg] + bh0);
        const float zz = sig_(gi.g1[rg] + a1[rg] + bh1);
        const float nn = tanh_(gi.g2[rg] + rr * (a2[rg] + bh2));
        const float hnew = (1.0f - zz) * nn + zz * hp[rg];
        const size_t so = ((size_t)colblk * 64 + b) * 16 + r16;
        stf_sc(hnF + so, hnew);
        sth_sc(hnB + so, hnew);
        if (yencD) stf_sc(yencD + (((size_t)colblk * 64 + b) * TE + tt) * 16 + r16, hnew);
        if (zrow)  sth_sc(zrow + (size_t)b * KZ + c, hnew);
    }
}

// attention step, 512-thread uniform barriers.
__device__ __forceinline__ void attn_step512(
    const float* __restrict__ yencL, float* __restrict__ h2s,
    float* __restrict__ scL, float* __restrict__ attwL,
    const float* __restrict__ h2g, int b, __bf16* __restrict__ zr,
    int* __restrict__ myflag, int* __restrict__ zflag, int postval)
{
    const int tid = threadIdx.x, lane = tid & 63, w = tid >> 6;

    float a0 = 0.f, a1 = 0.f;
    if (tid < HD) a0 = ldf_sc(h2g + hblk(b, tid));
    if (tid + 512 < HD) a1 = ldf_sc(h2g + hblk(b, tid + 512));
    vm_wait0();
    __builtin_amdgcn_sched_barrier(0);
    if (tid < HD) h2s[tid] = a0;
    if (tid + 512 < HD) h2s[tid + 512] = a1;
    __syncthreads();
    if (tid == 0) sti_sc(myflag, postval);

    const float2* h22 = (const float2*)h2s;
    for (int t = w; t < TE; t += 8) {
        const float2* y2 = (const float2*)(yencL + t * HD);
        float p = 0.f;
#pragma unroll
        for (int it = 0; it < HD / 128; ++it) {
            const float2 ya = y2[lane + it * 64];
            const float2 hb2 = h22[lane + it * 64];
            p += ya.x * hb2.x + ya.y * hb2.y;
        }
        p += __shfl_down(p, 32); p += __shfl_down(p, 16); p += __shfl_down(p, 8);
        p += __shfl_down(p, 4);  p += __shfl_down(p, 2);  p += __shfl_down(p, 1);
        if (lane == 0) scL[t] = p;
    }
    __syncthreads();

    float m = scL[0];
    for (int t = 1; t < TE; ++t) m = fmaxf(m, scL[t]);
    float s = 0.f;
    for (int t = 0; t < TE; ++t) s += __expf(scL[t] - m);
    const float inv = 1.0f / s;
    if (tid < TE) attwL[tid] = __expf(scL[tid] - m) * inv;
    __syncthreads();

    for (int c = tid; c < HD; c += 512) {
        float acc = 0.f;
#pragma unroll
        for (int t = 0; t < TE; ++t) acc += attwL[t] * yencL[t * HD + c];
        sth_sc(zr + (size_t)b * KZ + HD + c, acc);
    }
    vm_wait0();
    __syncthreads();
    if (tid == 0) sti_sc(zflag, postval);
}

// in-kernel 512-thread row softmax; reads logits via sc1 (L3), writes plain.
__device__ __forceinline__ void softmax512(float* row, float* red, float* red2,
                                           float* __restrict__ orow)
{
    const int tid = threadIdx.x, lane = tid & 63, w = tid >> 6;

    for (int it = 0; it < 3; ++it) {
        f32x4 v[5]; int jj[5]; bool ok[5];
#pragma unroll
        for (int u = 0; u < 5; ++u) {
            jj[u] = it * 2560 + u * 512 + tid;
            ok[u] = jj[u] < VO / 4;
            if (ok[u]) v[u] = ldf4_sc(orow + (size_t)jj[u] * 4);
        }
        vm_wait0();
        __builtin_amdgcn_sched_barrier(0);
#pragma unroll
        for (int u = 0; u < 5; ++u)
            if (ok[u]) *(f32x4*)&row[(size_t)jj[u] * 4] = v[u];
    }
    __syncthreads();

    float m = -1e30f;
    for (int ch = tid; ch < VO / 4; ch += 512) {
        const f32x4 x = *(const f32x4*)&row[ch * 4];
        m = fmaxf(fmaxf(fmaxf(m, x[0]), x[1]), fmaxf(x[2], x[3]));
    }
    m = fmaxf(m, __shfl_down(m, 32)); m = fmaxf(m, __shfl_down(m, 16));
    m = fmaxf(m, __shfl_down(m, 8));  m = fmaxf(m, __shfl_down(m, 4));
    m = fmaxf(m, __shfl_down(m, 2));  m = fmaxf(m, __shfl_down(m, 1));
    if (lane == 0) red[w] = m;
    __syncthreads();
    if (tid == 0) {
        float mm = red[0];
#pragma unroll
        for (int i = 1; i < 8; ++i) mm = fmaxf(mm, red[i]);
        red[0] = mm;
    }
    __syncthreads();
    m = red[0];

    float s = 0.0f;
    for (int v2 = tid; v2 < VO; v2 += 512) {
        const float e = __expf(row[v2] - m);
        row[v2] = e;
        s += e;
    }
    s += __shfl_down(s, 32); s += __shfl_down(s, 16); s += __shfl_down(s, 8);
    s += __shfl_down(s, 4);  s += __shfl_down(s, 2);  s += __shfl_down(s, 1);
    if (lane == 0) red2[w] = s;
    __syncthreads();
    if (tid == 0) {
        float ss = red2[0];
#pragma unroll
        for (int i = 1; i < 8; ++i) ss += red2[i];
        red2[0] = ss;
    }
    __syncthreads();
    s = red2[0];

    const float inv = 1.0f / s;
    for (int ch = tid; ch < VO / 4; ch += 512) {
        f32x4 x = *(const f32x4*)&row[ch * 4];
        x[0] *= inv; x[1] *= inv; x[2] *= inv; x[3] *= inv;
        *(f32x4*)&orow[(size_t)ch * 4] = x;   // plain: kernel-end release flushes
    }
    __syncthreads();
}

// ---------------------------------------------------------------------------
// Persistent kernel: recurrence roles (blocks 0..119) + fcW conversion (worker
// blocks 120..247 during encoder idle) + unified FC/softmax queue with rows
// DELAYED BY TWO GROUPS: tiles(0),tiles(1),[tiles(k),rows(k-2)]k=2..9,
// rows(8),rows(9) — avoids head-of-line blocking (r16 regression) while
// overlapping softmax of group g with FC of groups g+2.. .
// ---------------------------------------------------------------------------
__global__ __launch_bounds__(512, 1) void recur(
    const float* __restrict__ GIf, const float* __restrict__ GIb,
    const float* __restrict__ GId,
    const float* __restrict__ WhhF, const float* __restrict__ WhhB,
    const float* __restrict__ WhhD,
    const float* __restrict__ bhhF, const float* __restrict__ bhhB,
    const float* __restrict__ bhhD,
    float* __restrict__ heF, __bf16* __restrict__ heB,
    float* __restrict__ hdF, __bf16* __restrict__ hdB,
    float* __restrict__ yenc_f, float* __restrict__ yenc_b,
    __bf16* __restrict__ Zb, int* __restrict__ flags,
    const float* __restrict__ fcWsrc, __bf16* __restrict__ fcW,
    float* __restrict__ outC, const float* __restrict__ fcb)
{
    __shared__ __align__(16) char smem[147456];
    __bf16* wlds  = (__bf16*)smem;
    float*  yencL = (float*)smem;
    float*  h2s   = (float*)(smem + 143360);
    float*  scL   = (float*)(smem + 146944);
    float*  attwL = (float*)(smem + 147136);
    float*  redA  = (float*)(smem + 131072);
    float*  redB  = (float*)(smem + 131136);
    volatile int* shtile = (volatile int*)(smem + 147400);

    const int gid = blockIdx.x;
    const int tid = threadIdx.x;
    const int lane = tid & 63, w = tid >> 6;
    const int r16 = lane & 15, hi = lane >> 4;
    const size_t S = (size_t)BB * HD;

    if (gid < NBLK) {
        float bb0 = 0.f, bb1 = 0.f, bb2 = 0.f;
        GiReg gi;

        // ================= encoder =================
        if (gid < 112) {
            const int dir = (gid >= 56) ? 1 : 0;
            const int gloc = dir ? gid - 56 : gid;
            const int c0e = gloc * 16;
            const float* GIe  = dir ? GIb : GIf;
            const float* bhhE = dir ? bhhB : bhhF;
            float* yencD = dir ? yenc_b : yenc_f;
            const int foff = dir ? BOFF : FOFF;
            const int ce = c0e + r16;

            stage_w(wlds, dir ? WhhB : WhhF, c0e);
            if (tid < 256) {
                bb0 = bhhE[ce]; bb1 = bhhE[HD + ce]; bb2 = bhhE[2 * HD + ce];
                gi = gi_prefetch(GIe + (size_t)(dir ? TE - 1 : 0) * BB * G3, ce, w, hi);
            }
            __syncthreads();

            for (int t = 0; t < TE; ++t) {
                if (t > 0) {
                    if (tid < 56) spin_ge(flags + (foff + tid) * FSTR, t);
                    __syncthreads();
                }
                const int tt = dir ? (TE - 1 - t) : t;
                if (tid < 256)
                    gru_step(heB + (size_t)(dir * 2 + (t & 1)) * S,
                             heF + (size_t)(dir * 2 + (t & 1)) * S,
                             wlds, gi, bb0, bb1, bb2,
                             heF + (size_t)(dir * 2 + ((t + 1) & 1)) * S,
                             heB + (size_t)(dir * 2 + ((t + 1) & 1)) * S,
                             yencD, tt, nullptr, c0e, lane, w);
                vm_wait0();
                __syncthreads();
                if (tid == 0) sti_sc(flags + (foff + gloc) * FSTR, t + 1);
                if (t + 1 < TE && tid < 256) {
                    const int ttn = dir ? (TE - 2 - t) : (t + 1);
                    gi = gi_prefetch(GIe + (size_t)ttn * BB * G3, ce, w, hi);
                }
            }
        }

        // ================= transition =================
        if (tid < 112) spin_ge(flags + tid * FSTR, TE);
        __syncthreads();

        {
            const int i0 = gid * 256 + tid;
            const int i1 = i0 + NBLK * 256;
            const bool has0 = (i0 < BB * HD);
            const bool has1 = (i1 < BB * HD);
            const float f0 = has0 ? ldf_sc(&heF[0 * S + i0]) : 0.f;
            const float b0 = has0 ? ldf_sc(&heF[2 * S + i0]) : 0.f;
            const float f1 = has1 ? ldf_sc(&heF[0 * S + i1]) : 0.f;
            const float b1 = has1 ? ldf_sc(&heF[2 * S + i1]) : 0.f;
            vm_wait0();
            __builtin_amdgcn_sched_barrier(0);
            if (has0) { const float v0 = f0 + b0; stf_sc(&hdF[i0], v0); sth_sc(&hdB[i0], v0); }
            if (has1) { const float v1 = f1 + b1; stf_sc(&hdF[i1], v1); sth_sc(&hdB[i1], v1); }
        }
        if (gid < 56) {
            stage_w(wlds, WhhD, gid * 16);
            if (tid < 256) {
                const int cd = gid * 16 + r16;
                bb0 = bhhD[cd]; bb1 = bhhD[HD + cd]; bb2 = bhhD[2 * HD + cd];
                gi = gi_prefetch(GId, cd, w, hi);
            }
        }
        vm_wait0();
        __syncthreads();
        if (tid == 0) sti_sc(flags + (TOFF + gid) * FSTR, 1);
        if (tid < 120) spin_ge(flags + (TOFF + tid) * FSTR, 1);
        __syncthreads();

        // ================= decoder =================
        if (gid < 56) {
            for (int p = 0; p < TD; ++p) {
                if (p > 0 && tid < 56) spin_ge(flags + (DOFF + tid) * FSTR, p);
                if (p >= 4 && tid >= 64 && tid < 128)
                    spin_ge(flags + (AOFF + tid - 64) * FSTR, p - 3);
                __syncthreads();
                if (tid < 256)
                    gru_step(hdB + (size_t)(p & 3) * S, hdF + (size_t)(p & 3) * S,
                             wlds, gi, bb0, bb1, bb2,
                             hdF + (size_t)((p + 1) & 3) * S, hdB + (size_t)((p + 1) & 3) * S,
                             nullptr, 0, Zb + (size_t)p * BB * KZ, gid * 16, lane, w);
                vm_wait0();
                __syncthreads();
                if (tid == 0) sti_sc(flags + (DOFF + gid) * FSTR, p + 1);
                if (p + 1 < TD && tid < 256)
                    gi = gi_prefetch(GId + (size_t)(p + 1) * BB * G3, gid * 16 + r16, w, hi);
            }
        } else {
            const int b = gid - 56;
            const float* sf = yenc_f;
            const float* sb = yenc_b;
            for (int it = 0; it < 4; ++it) {
                f32x4 a_[5], b_[5];
                int tt_[5], gg_[5], cc_[5]; bool ok[5];
#pragma unroll
                for (int u = 0; u < 5; ++u) {
                    const int j = it * 2560 + u * 512 + tid;
                    ok[u] = (j < 8960);
                    if (ok[u]) {
                        gg_[u] = j / 160;
                        const int rem = j - gg_[u] * 160;
                        tt_[u] = rem >> 2;
                        cc_[u] = (rem & 3) * 4;
                        const size_t sa = (((size_t)gg_[u] * 64 + b) * TE + tt_[u]) * 16 + cc_[u];
                        a_[u] = ldf4_sc(sf + sa);
                        b_[u] = ldf4_sc(sb + sa);
                    }
                }
                vm_wait0();
                __builtin_amdgcn_sched_barrier(0);
#pragma unroll
                for (int u = 0; u < 5; ++u)
                    if (ok[u])
                        *(f32x4*)&yencL[(size_t)tt_[u] * HD + gg_[u] * 16 + cc_[u]] = a_[u] + b_[u];
            }
            __syncthreads();
            for (int s = 0; s < TD; ++s) {
                if (tid < 56) spin_ge(flags + (DOFF + tid) * FSTR, s + 1);
                __syncthreads();
                attn_step512(yencL, h2s, scL, attwL, hdF + (size_t)((s + 1) & 3) * S,
                             b, Zb + (size_t)s * BB * KZ,
                             flags + (AOFF + b) * FSTR, flags + (ZOFF + b) * FSTR, s + 1);
            }
        }
    } else {
        // ============ worker blocks: convert fcW fp32->bf16 (sc1) ============
        const int slice = gid - NBLK;                    // 0..127
        const size_t base = (size_t)slice * 236 * KZ;    // 236 rows per slice
        const int nf4 = 236 * KZ / 4;
        for (int i = tid; i < nf4; i += 512) {
            const size_t e0 = base + (size_t)i * 4;
            const int r = (int)(e0 / KZ);
            u16x4 o;
            if (r < VO) {
                const float4 x = *(const float4*)&fcWsrc[e0];
                o.x = __builtin_bit_cast(unsigned short, (__bf16)x.x);
                o.y = __builtin_bit_cast(unsigned short, (__bf16)x.y);
                o.z = __builtin_bit_cast(unsigned short, (__bf16)x.z);
                o.w = __builtin_bit_cast(unsigned short, (__bf16)x.w);
            } else {
                o.x = 0; o.y = 0; o.z = 0; o.w = 0;
            }
            st8_sc(&fcW[e0], o);
        }
        vm_wait0();
        __syncthreads();
        if (tid == 0)
            __hip_atomic_fetch_add(flags + FWC * FSTR, 1, __ATOMIC_RELAXED,
                                   __HIP_MEMORY_SCOPE_AGENT);
    }

    // ============ unified FC + softmax queue (rows delayed 2 groups) ========
    {
        __bf16* lds = (__bf16*)smem;
        const int wave = tid >> 6;
        const int wm = wave >> 2, wn = wave & 3;
        int* qcnt = flags + QOFF * FSTR;

        if (tid == 0) spinb(flags + FWC * FSTR, 128);   // fcW conversion done
        __syncthreads();

        const int srow0 = wave * 8 + (lane >> 3);
        const int scol  = ((lane & 7) ^ (lane >> 3)) * 8;
        const int cbx0 = ((hi * 16) ^ ((r16 & 7) << 4)) >> 1;
        const int cbx1 = ((64 + hi * 16) ^ ((r16 & 7) << 4)) >> 1;

        for (;;) {
            if (tid == 0) {
                const int tl = __hip_atomic_fetch_add(qcnt, 1, __ATOMIC_RELAXED,
                                                      __HIP_MEMORY_SCOPE_AGENT);
                *shtile = tl;
            }
            __syncthreads();
            const int item = *shtile;
            if (item >= NITEM) break;

            // map item -> (isRow, mt, idx): tiles(0),tiles(1),
            // then for k=2..9: tiles(k), rows(k-2); then rows(8), rows(9)
            int rem = item, mt = 0, idx = 0;
            bool isRow = false;
#pragma unroll 1
            for (int k = 0; k < 12; ++k) {
                if (k < 10) {
                    if (rem < NTN) { isRow = false; mt = k; idx = rem; break; }
                    rem -= NTN;
                }
                if (k >= 2) {
                    if (rem < 256) { isRow = true; mt = k - 2; idx = rem; break; }
                    rem -= 256;
                }
            }

            if (isRow) {
                // -------- softmax row item: gate on group's FC completion ----
                if (tid == 0) spinb(flags + (MTO + mt) * FSTR, NTN);
                __syncthreads();
                const int t = 4 * mt + (idx >> 6), b = idx & 63;
                softmax512((float*)smem, redA, redB, outC + (size_t)(b * TD + t) * VO);
                continue;
            }

            // -------- FC tile item --------
            const int nt = idx;
            const int need = 4 * mt + 4;
            if (tid < 56) spinb(flags + (DOFF + tid) * FSTR, need);
            if (tid >= 64 && tid < 128) spinb(flags + (ZOFF + tid - 64) * FSTR, need);
            __syncthreads();

            const long tileM = (long)mt * 256;
            const long tileN = (long)nt * 256;
            const __bf16* gAh[2] = { Zb + (size_t)tileM * KZ, Zb + (size_t)(tileM + 128) * KZ };
            const __bf16* gBh[2] = { fcW + (size_t)tileN * KZ, fcW + (size_t)(tileN + 128) * KZ };
            auto Abase = [](int buf, int h) { return (buf * 2 + h) * 8192; };
            auto Bbase = [](int buf, int h) { return 32768 + (buf * 2 + h) * 8192; };
            auto stageA = [&](const __bf16* gph, int kt, int lbase) {
                const __bf16* g0 = gph + (size_t)srow0 * KZ + kt * 64 + scol;
                gload_lds16_sc(g0, &lds[lbase + wave * 512]);
                gload_lds16_sc(g0 + (size_t)64 * KZ, &lds[lbase + (8 + wave) * 512]);
            };
            auto stageB = [&](const __bf16* gph, int kt, int lbase) {
                const __bf16* g0 = gph + (size_t)srow0 * KZ + kt * 64 + scol;
                gload_lds16(g0, &lds[lbase + wave * 512]);
                gload_lds16(g0 + (size_t)64 * KZ, &lds[lbase + (8 + wave) * 512]);
            };

            f32x4 acc[8][4];
            const f32x4 zero = {0.f, 0.f, 0.f, 0.f};
#pragma unroll
            for (int m = 0; m < 8; ++m)
#pragma unroll
                for (int n = 0; n < 4; ++n) acc[m][n] = zero;

            stageA(gAh[0], 0, Abase(0, 0));
            stageA(gAh[1], 0, Abase(0, 1));
            stageB(gBh[0], 0, Bbase(0, 0));
            stageB(gBh[1], 0, Bbase(0, 1));
            stageB(gBh[0], 1, Bbase(1, 0));
            stageB(gBh[1], 1, Bbase(1, 1));
            asm volatile("s_waitcnt vmcnt(4)" ::: "memory");
            __builtin_amdgcn_s_barrier();

            for (int kt = 0; kt < KT; ++kt) {
                const int buf = kt & 1;
                const int kn1 = (kt + 1 < KT) ? kt + 1 : 0;
                const int kn2 = (kt + 2 < KT) ? kt + 2 : 0;
                const int Ab = Abase(buf, wm);
                const int Bb = Bbase(buf, wn >> 1);
                bf16x8 bfr[4][2];
#pragma unroll
                for (int q = 0; q < 4; ++q) {
                    if (q == 0) {
#pragma unroll
                        for (int n = 0; n < 4; ++n) {
                            const int rowB = (wn & 1) * 64 + n * 16 + r16;
                            bfr[n][0] = *(const bf16x8*)&lds[Bb + rowB * 64 + cbx0];
                            bfr[n][1] = *(const bf16x8*)&lds[Bb + rowB * 64 + cbx1];
                        }
                    }
                    bf16x8 af[2][2];
#pragma unroll
                    for (int mm = 0; mm < 2; ++mm) {
                        const int rowA = (q * 2 + mm) * 16 + r16;
                        af[mm][0] = *(const bf16x8*)&lds[Ab + rowA * 64 + cbx0];
                        af[mm][1] = *(const bf16x8*)&lds[Ab + rowA * 64 + cbx1];
                    }
                    if (q == 0)      stageA(gAh[0], kn1, Abase(buf ^ 1, 0));
                    else if (q == 1) stageA(gAh[1], kn1, Abase(buf ^ 1, 1));
                    else if (q == 2) stageB(gBh[0], kn2, Bbase(buf, 0));
                    else {
                        stageB(gBh[1], kn2, Bbase(buf, 1));
                        asm volatile("s_waitcnt vmcnt(4)" ::: "memory");
                    }
                    __builtin_amdgcn_s_barrier();
                    asm volatile("s_waitcnt lgkmcnt(0)" ::: "memory");
                    __builtin_amdgcn_sched_barrier(0);
                    __builtin_amdgcn_s_setprio(1);
#pragma unroll
                    for (int mm = 0; mm < 2; ++mm)
#pragma unroll
                        for (int n = 0; n < 4; ++n) {
                            acc[q * 2 + mm][n] = __builtin_amdgcn_mfma_f32_16x16x32_bf16(
                                af[mm][0], bfr[n][0], acc[q * 2 + mm][n], 0, 0, 0);
                            acc[q * 2 + mm][n] = __builtin_amdgcn_mfma_f32_16x16x32_bf16(
                                af[mm][1], bfr[n][1], acc[q * 2 + mm][n], 0, 0, 0);
                        }
                    __builtin_amdgcn_s_setprio(0);
                    __builtin_amdgcn_sched_barrier(0);
                    __builtin_amdgcn_s_barrier();
                }
            }
            asm volatile("s_waitcnt vmcnt(0)" ::: "memory");

            // epilogue: sc1 stores (read back in-kernel by softmax), then MT inc
#pragma unroll
            for (int m = 0; m < 8; ++m) {
#pragma unroll
                for (int n = 0; n < 4; ++n) {
                    const long gcol = tileN + wn * 64 + n * 16 + r16;
                    if (gcol >= VO) continue;
                    const float bv = fcb[gcol];
#pragma unroll
                    for (int rr = 0; rr < 4; ++rr) {
                        const long grow = tileM + wm * 128 + m * 16 + hi * 4 + rr;
                        const long t = grow >> 6, b = grow & 63;
                        stf_sc(&outC[(b * TD + t) * VO + gcol], acc[m][n][rr] + bv);
                    }
                }
            }
            vm_wait0();
            __syncthreads();
            if (tid == 0)
                __hip_atomic_fetch_add(flags + (MTO + mt) * FSTR, 1, __ATOMIC_RELAXED,
                                       __HIP_MEMORY_SCOPE_AGENT);
            __syncthreads();
        }
    }
}

// ---------------------------------------------------------------------------
// 128^2 T3+T4 GEMM (proven): input-side GEMMs. fp32 C.
// ---------------------------------------------------------------------------
__global__ __launch_bounds__(256) void gemm_bt(
    const __bf16* __restrict__ A0, const __bf16* __restrict__ B0,
    float* __restrict__ C0, const float* __restrict__ bias0,
    const __bf16* __restrict__ A1, const __bf16* __restrict__ B1,
    float* __restrict__ C1, const float* __restrict__ bias1,
    int M, int N, int K)
{
    constexpr int BM = 128, BN = 128, BK = 32;
    constexpr int FM = 4, FN = 4;

    const __bf16* A = A0; const __bf16* Bp = B0;
    float* C = C0; const float* bias = bias0;
    if (blockIdx.z == 1) { A = A1; Bp = B1; C = C1; bias = bias1; }

    __shared__ __bf16 Ash[2][BM * BK];
    __shared__ __bf16 Bsh[2][BN * BK];

    const int tid  = threadIdx.x;
    const int lane = tid & 63;
    const int wave = tid >> 6;
    const int wr = wave >> 1, wc = wave & 1;

    const int nwg = gridDim.x * gridDim.y;
    const int orig = blockIdx.y * gridDim.x + blockIdx.x;
    const int q = nwg >> 3, r = nwg & 7;
    const int xcd = orig & 7, idx = orig >> 3;
    const int wg = (xcd < r ? xcd * (q + 1) : r * (q + 1) + (xcd - r) * q) + idx;
    const int mtiles = gridDim.y;
    const long tileM = (long)(wg % mtiles) * BM;
    const long tileN = (long)(wg / mtiles) * BN;

    const int r16 = lane & 15;
    const int hi  = lane >> 4;

    f32x4 acc[FM][FN];
    const f32x4 zero = {0.f, 0.f, 0.f, 0.f};
#pragma unroll
    for (int m = 0; m < FM; ++m)
#pragma unroll
        for (int n = 0; n < FN; ++n) acc[m][n] = zero;

    const int srow = wave * 32 + (lane >> 2);
    const int schunk = (lane & 3) * 8;
    const __bf16* gA = A + (size_t)(tileM + srow) * K + schunk;
    const __bf16* gB = Bp + (size_t)(tileN + srow) * K + schunk;
    const size_t kstep16 = (size_t)16 * K;
    const int lofs = (wave * 32) * BK;

#define STAGE_T(k0_, sel_)                                            \
    do {                                                              \
        gload_lds16(gA + (k0_), &Ash[sel_][lofs]);                    \
        gload_lds16(gA + (k0_) + kstep16, &Ash[sel_][lofs + 16 * BK]);\
        gload_lds16(gB + (k0_), &Bsh[sel_][lofs]);                    \
        gload_lds16(gB + (k0_) + kstep16, &Bsh[sel_][lofs + 16 * BK]);\
    } while (0)

    STAGE_T(0, 0);
    int cur = 0;
    for (int k0 = BK; k0 < K; k0 += BK) {
        STAGE_T(k0, cur ^ 1);
        asm volatile("s_waitcnt vmcnt(4)" ::: "memory");
        __builtin_amdgcn_s_barrier();
        __builtin_amdgcn_sched_barrier(0);

        bf16x8 af[FM], bfr[FN];
#pragma unroll
        for (int m = 0; m < FM; ++m)
            af[m] = *(const bf16x8*)&Ash[cur][(wr * 64 + m * 16 + r16) * BK + hi * 8];
#pragma unroll
        for (int n = 0; n < FN; ++n)
            bfr[n] = *(const bf16x8*)&Bsh[cur][(wc * 64 + n * 16 + r16) * BK + hi * 8];
#pragma unroll
        for (int m = 0; m < FM; ++m)
#pragma unroll
            for (int n = 0; n < FN; ++n)
                acc[m][n] = __builtin_amdgcn_mfma_f32_16x16x32_bf16(af[m], bfr[n], acc[m][n], 0, 0, 0);

        __builtin_amdgcn_sched_barrier(0);
        __builtin_amdgcn_s_barrier();
        __builtin_amdgcn_sched_barrier(0);
        cur ^= 1;
    }
    asm volatile("s_waitcnt vmcnt(0)" ::: "memory");
    __builtin_amdgcn_s_barrier();
    __builtin_amdgcn_sched_barrier(0);
    {
        bf16x8 af[FM], bfr[FN];
#pragma unroll
        for (int m = 0; m < FM; ++m)
            af[m] = *(const bf16x8*)&Ash[cur][(wr * 64 + m * 16 + r16) * BK + hi * 8];
#pragma unroll
        for (int n = 0; n < FN; ++n)
            bfr[n] = *(const bf16x8*)&Bsh[cur][(wc * 64 + n * 16 + r16) * BK + hi * 8];
#pragma unroll
        for (int m = 0; m < FM; ++m)
#pragma unroll
            for (int n = 0; n < FN; ++n)
                acc[m][n] = __builtin_amdgcn_mfma_f32_16x16x32_bf16(af[m], bfr[n], acc[m][n], 0, 0, 0);
    }
#undef STAGE_T

#pragma unroll
    for (int m = 0; m < FM; ++m) {
#pragma unroll
        for (int n = 0; n < FN; ++n) {
            const long gcol = tileN + wc * 64 + n * 16 + r16;
            const float bv = bias ? bias[gcol] : 0.0f;
#pragma unroll
            for (int rr = 0; rr < 4; ++rr) {
                const long grow = tileM + wr * 64 + m * 16 + hi * 4 + rr;
                C[grow * N + gcol] = acc[m][n][rr] + bv;
            }
        }
    }
}

// fp32 -> bf16 convert with row/col zero-padding (small Wih matrices)
__global__ __launch_bounds__(256) void conv_pad(const float* __restrict__ src,
                                                __bf16* __restrict__ dst,
                                                int Rout, int Rin, int Kout, int Kin)
{
    size_t i = (size_t)blockIdx.x * 256 + threadIdx.x;
    const size_t total = (size_t)Rout * Kout;
    const size_t stride = (size_t)gridDim.x * 256;
    for (; i < total; i += stride) {
        int k = (int)(i % Kout);
        int r = (int)(i / Kout);
        float v = (r < Rin && k < Kin) ? src[(size_t)r * Kin + k] : 0.0f;
        dst[i] = (__bf16)v;
    }
}

// gather token embeddings into padded bf16 matrix X[(t*B+b)][EP]
__global__ __launch_bounds__(256) void gather_embed(const int* __restrict__ tok,
                                                    const float* __restrict__ emb,
                                                    __bf16* __restrict__ X)
{
    int i = blockIdx.x * 256 + threadIdx.x;
    const int total = TE * BB * EP;
    for (; i < total; i += gridDim.x * 256) {
        int e = i % EP;
        int row = i / EP;
        int t = row >> 6, b = row & 63;
        float v = 0.0f;
        if (e < ED) v = emb[(size_t)tok[b * TE + t] * ED + e];
        X[i] = (__bf16)v;
    }
}

extern "C" void kernel_launch(void* const* d_in, const int* in_sizes, int n_in,
                              void* d_out, int out_size, void* d_ws, size_t ws_size,
                              hipStream_t stream)
{
    if (n_in < 18) return;
    const int*   x_enc   = (const int*)d_in[0];
    const int*   x_dec   = (const int*)d_in[1];
    const float* emb_enc = (const float*)d_in[2];
    const float* Wih_f   = (const float*)d_in[3];
    const float* Whh_f   = (const float*)d_in[4];
    const float* bih_f   = (const float*)d_in[5];
    const float* bhh_f   = (const float*)d_in[6];
    const float* Wih_b   = (const float*)d_in[7];
    const float* Whh_b   = (const float*)d_in[8];
    const float* bih_b   = (const float*)d_in[9];
    const float* bhh_b   = (const float*)d_in[10];
    const float* emb_dec = (const float*)d_in[11];
    const float* Wih_d   = (const float*)d_in[12];
    const float* Whh_d   = (const float*)d_in[13];
    const float* bih_d   = (const float*)d_in[14];
    const float* bhh_d   = (const float*)d_in[15];
    const float* fc_W    = (const float*)d_in[16];
    const float* fc_b    = (const float*)d_in[17];
    float* out = (float*)d_out;

    size_t off = 0;
    auto alloc = [&](size_t bytes) -> void* {
        void* p = (char*)d_ws + off;
        off = (off + bytes + 255) & ~(size_t)255;
        return p;
    };
    __bf16* fcWb   = (__bf16*)alloc((size_t)VP2 * KZ * 2);
    __bf16* WihFb  = (__bf16*)alloc((size_t)G3 * EP * 2);
    __bf16* WihBb  = (__bf16*)alloc((size_t)G3 * EP * 2);
    __bf16* WihDb  = (__bf16*)alloc((size_t)G3 * EP * 2);
    __bf16* Xe     = (__bf16*)alloc((size_t)MR * EP * 2);
    __bf16* Xd     = (__bf16*)alloc((size_t)MR * EP * 2);
    float*  GIf    = (float*)alloc((size_t)MR * G3 * 4);
    float*  GIb    = (float*)alloc((size_t)MR * G3 * 4);
    float*  GId    = (float*)alloc((size_t)MR * G3 * 4);
    __bf16* Zb     = (__bf16*)alloc((size_t)MR * KZ * 2);
    float*  yenc_f = (float*)alloc((size_t)BB * TE * HD * 4);
    float*  yenc_b = (float*)alloc((size_t)BB * TE * HD * 4);
    float*  hdF    = (float*)alloc((size_t)4 * BB * HD * 4);
    __bf16* hdB    = (__bf16*)alloc((size_t)4 * BB * HD * 2);
    char* zero_start = (char*)d_ws + off;
    float*  heF    = (float*)alloc((size_t)4 * BB * HD * 4);
    __bf16* heB    = (__bf16*)alloc((size_t)4 * BB * HD * 2);
    int*    flags  = (int*)alloc(512 * FSTR * 4);
    size_t zero_bytes = (size_t)(((char*)d_ws + off) - zero_start);
    if (off > ws_size) return;   // ~230 MB required; fail visibly (zero output)

    // ---- init + small weight conversion + embedding gather ----
    hipMemsetAsync(zero_start, 0, zero_bytes, stream);
    conv_pad<<<3360, 256, 0, stream>>>(Wih_f, WihFb, G3, G3, EP, ED);
    conv_pad<<<3360, 256, 0, stream>>>(Wih_b, WihBb, G3, G3, EP, ED);
    conv_pad<<<3360, 256, 0, stream>>>(Wih_d, WihDb, G3, G3, EP, ED);
    gather_embed<<<3200, 256, 0, stream>>>(x_enc, emb_enc, Xe);
    gather_embed<<<3200, 256, 0, stream>>>(x_dec, emb_dec, Xd);

    // ---- batched input-side GEMMs: GI = X @ Wih^T + bih ----
    gemm_bt<<<dim3(G3 / 128, MR / 128, 2), 256, 0, stream>>>(
        Xe, WihFb, GIf, bih_f, Xe, WihBb, GIb, bih_b, MR, G3, EP);
    gemm_bt<<<dim3(G3 / 128, MR / 128, 1), 256, 0, stream>>>(
        Xd, WihDb, GId, bih_d, nullptr, nullptr, nullptr, nullptr, MR, G3, EP);

    // ---- persistent: recurrence + fcW conversion + FC + softmax (one kernel) --
    recur<<<NWB, 512, 0, stream>>>(GIf, GIb, GId, Whh_f, Whh_b, Whh_d,
                                   bhh_f, bhh_b, bhh_d,
                                   heF, heB, hdF, hdB, yenc_f, yenc_b, Zb, flags,
                                   fc_W, fcWb, out, fc_b);
}

// Round 18
// 890.922 us; speedup vs baseline: 1.4621x; 1.1275x over previous
//
#include <hip/hip_runtime.h>

// ---- problem constants ----
#define BB 64      // batch
#define TE 40      // encoder steps
#define TD 40      // decoder steps
#define ED 300     // embedding dim
#define EP 320     // padded embedding dim
#define HD 896     // hidden
#define G3 2688    // 3*H
#define VO 30000   // vocab out
#define VP2 30208  // padded vocab (118*256)
#define KZ 1792    // 2*H
#define KT 28      // KZ/64 K-tiles for the 256^2 FC GEMM
#define MR 2560    // T*B rows
#define NBLK 120   // recur role blocks
#define NWB 248    // total blocks (120 roles + 128 FC workers; <=256 CUs)
#define NTN 118    // FC N-tiles
#define NTILE (NTN * 10)

// flag regions (flag index; each flag occupies its own 128-B cacheline)
#define FOFF 0     // encoder fwd, 56
#define BOFF 56    // encoder bwd, 56
#define DOFF 112   // decoder GRU, 56
#define AOFF 168   // decoder attn h-slot credit, 64
#define TOFF 232   // transition, 120
#define ZOFF 352   // attn ctx written+drained, 64
#define QOFF 448   // FC tile queue counter
#define FWC  456   // fcW conversion completion counter (target 128)
#define FSTR 32    // ints per flag line (128 B)

typedef __attribute__((ext_vector_type(8))) __bf16 bf16x8;
typedef __attribute__((ext_vector_type(4))) float f32x4;
typedef __attribute__((ext_vector_type(4))) unsigned int u32x4;
typedef __attribute__((ext_vector_type(4))) unsigned short u16x4;

typedef __attribute__((address_space(1))) const void av1c;
typedef __attribute__((address_space(3))) void av3;

__device__ __forceinline__ float sig_(float x)  { return 1.0f / (1.0f + __expf(-x)); }
__device__ __forceinline__ float tanh_(float x) { return 1.0f - 2.0f / (__expf(2.0f * x) + 1.0f); }

// async global->LDS, 16B/lane (linear dest). aux=0 plain; aux=17 = sc0|sc1.
__device__ __forceinline__ void gload_lds16(const __bf16* g, __bf16* l) {
    __builtin_amdgcn_global_load_lds((av1c*)g, (av3*)l, 16, 0, 0);
}
__device__ __forceinline__ void gload_lds16_sc(const __bf16* g, __bf16* l) {
    __builtin_amdgcn_global_load_lds((av1c*)g, (av3*)l, 16, 0, 17);
}

// ---- coherent (cross-XCD) access helpers: sc0 sc1 = L3 coherence point ----
__device__ __forceinline__ bf16x8 ld128_sc(const __bf16* p) {
    bf16x8 r;
    asm volatile("global_load_dwordx4 %0, %1, off sc0 sc1" : "=v"(r) : "v"(p));
    return r;
}
__device__ __forceinline__ f32x4 ldf4_sc(const float* p) {
    f32x4 r;
    asm volatile("global_load_dwordx4 %0, %1, off sc0 sc1" : "=v"(r) : "v"(p));
    return r;
}
__device__ __forceinline__ float ldf_sc(const float* p) {
    float r;
    asm volatile("global_load_dword %0, %1, off sc0 sc1" : "=v"(r) : "v"(p));
    return r;
}
__device__ __forceinline__ void vm_wait0() {
    asm volatile("s_waitcnt vmcnt(0)" ::: "memory");
}
__device__ __forceinline__ void stf_sc(float* p, float v) {
    asm volatile("global_store_dword %0, %1, off sc0 sc1" :: "v"(p), "v"(v) : "memory");
}
__device__ __forceinline__ void sth_sc(__bf16* p, float v) {
    unsigned int u = (unsigned int)__builtin_bit_cast(unsigned short, (__bf16)v);
    asm volatile("global_store_short %0, %1, off sc0 sc1" :: "v"(p), "v"(u) : "memory");
}
__device__ __forceinline__ void st8_sc(__bf16* p, u16x4 v) {
    asm volatile("global_store_dwordx2 %0, %1, off sc0 sc1" :: "v"(p), "v"(v) : "memory");
}
__device__ __forceinline__ void sti_sc(int* p, int v) {
    asm volatile("global_store_dword %0, %1, off sc0 sc1" :: "v"(p), "v"(v) : "memory");
}
// unbounded spin (role chains; co-residency proven structure)
__device__ __forceinline__ void spin_ge(const int* p, int target) {
    int v;
    for (;;) {
        asm volatile("global_load_dword %0, %1, off sc0 sc1\n\ts_waitcnt vmcnt(0)"
                     : "=v"(v) : "v"(p) : "memory");
        if (v >= target) break;
        __builtin_amdgcn_s_sleep(1);
    }
}
// bounded spin (FC dep edges; expiry -> wrong output, caught by absmax)
__device__ __forceinline__ void spinb(const int* p, int target) {
    for (int it = 0; it < (1 << 20); ++it) {
        int v;
        asm volatile("global_load_dword %0, %1, off sc0 sc1\n\ts_waitcnt vmcnt(0)"
                     : "=v"(v) : "v"(p) : "memory");
        if (v >= target) return;
        __builtin_amdgcn_s_sleep(16);
    }
}

// ---- line-exclusive blocked h layout: element (b, c) -> [(c>>4)*64 + b][c&15]
__device__ __forceinline__ size_t hblk(int b, int c) {
    return ((size_t)(c >> 4) * 64 + b) * 16 + (c & 15);
}

// Stage 48 Whh rows fp32 -> bf16 LDS in fragment order.
__device__ __forceinline__ void stage_w(__bf16* wlds, const float* __restrict__ W, int c0)
{
    const int tid = threadIdx.x;
    for (int ch = tid; ch < 48 * 224; ch += 256) {
        const int lr = ch / 224, c4 = (ch % 224) * 4;
        const int g = lr >> 4, rr = lr & 15;
        const int kk = c4 >> 5, hi = (c4 & 31) >> 3, j = c4 & 7;
        const float4 v = *(const float4*)&W[(size_t)(g * HD + c0 + rr) * HD + c4];
        __bf16* d = &wlds[((g * 28 + kk) * 64 + hi * 16 + rr) * 8 + j];
        d[0] = (__bf16)v.x; d[1] = (__bf16)v.y; d[2] = (__bf16)v.z; d[3] = (__bf16)v.w;
    }
}

struct GiReg { float g0[4], g1[4], g2[4]; };

__device__ __forceinline__ GiReg gi_prefetch(const float* __restrict__ GIt,
                                             int c, int w, int hi)
{
    GiReg r;
#pragma unroll
    for (int rg = 0; rg < 4; ++rg) {
        const float* gp = GIt + (size_t)(16 * w + hi * 4 + rg) * G3 + c;
        r.g0[rg] = gp[0]; r.g1[rg] = gp[HD]; r.g2[rg] = gp[2 * HD];
    }
    return r;
}

// One GRU step (tid<256 only; no internal barriers). Blocked h; Zb sc1.
__device__ __forceinline__ void gru_step(
    const __bf16* __restrict__ hcurB, const float* __restrict__ hcurF,
    const __bf16* __restrict__ wlds, const GiReg& gi,
    float bh0, float bh1, float bh2,
    float* __restrict__ hnF, __bf16* __restrict__ hnB,
    float* __restrict__ yencD, int tt,
    __bf16* __restrict__ zrow,
    int c0, int lane, int w)
{
    const int r16 = lane & 15, hi = lane >> 4;
    const int c = c0 + r16;
    const int colblk = c0 >> 4;
    const int brow = 16 * w;

    bf16x8 afr[28];
    const __bf16* ap = hcurB + ((size_t)(hi >> 1) * 64 + brow + r16) * 16 + (hi & 1) * 8;
#pragma unroll
    for (int kk = 0; kk < 28; ++kk) afr[kk] = ld128_sc(ap + kk * 2048);
    float hp[4];
#pragma unroll
    for (int rg = 0; rg < 4; ++rg)
        hp[rg] = ldf_sc(hcurF + ((size_t)colblk * 64 + brow + hi * 4 + rg) * 16 + r16);
    vm_wait0();
    __builtin_amdgcn_sched_barrier(0);

    f32x4 a0 = {0.f, 0.f, 0.f, 0.f}, a1 = a0, a2 = a0;
#pragma unroll
    for (int kk = 0; kk < 28; ++kk) {
        const bf16x8 b0 = *(const bf16x8*)&wlds[(kk) * 512 + lane * 8];
        const bf16x8 b1 = *(const bf16x8*)&wlds[(28 + kk) * 512 + lane * 8];
        const bf16x8 b2 = *(const bf16x8*)&wlds[(56 + kk) * 512 + lane * 8];
        a0 = __builtin_amdgcn_mfma_f32_16x16x32_bf16(afr[kk], b0, a0, 0, 0, 0);
        a1 = __builtin_amdgcn_mfma_f32_16x16x32_bf16(afr[kk], b1, a1, 0, 0, 0);
        a2 = __builtin_amdgcn_mfma_f32_16x16x32_bf16(afr[kk], b2, a2, 0, 0, 0);
    }

#pragma unroll
    for (int rg = 0; rg < 4; ++rg) {
        const int b = brow + hi * 4 + rg;
        const float rr = sig_(gi.g0[rg] + a0[rg] + bh0);
        const float zz = sig_(gi.g1[rg] + a1[rg] + bh1);
        const float nn = tanh_(gi.g2[rg] + rr * (a2[rg] + bh2));
        const float hnew = (1.0f - zz) * nn + zz * hp[rg];
        const size_t so = ((size_t)colblk * 64 + b) * 16 + r16;
        stf_sc(hnF + so, hnew);
        sth_sc(hnB + so, hnew);
        if (yencD) stf_sc(yencD + (((size_t)colblk * 64 + b) * TE + tt) * 16 + r16, hnew);
        if (zrow)  sth_sc(zrow + (size_t)b * KZ + c, hnew);
    }
}

// attention step, 512-thread uniform barriers.
__device__ __forceinline__ void attn_step512(
    const float* __restrict__ yencL, float* __restrict__ h2s,
    float* __restrict__ scL, float* __restrict__ attwL,
    const float* __restrict__ h2g, int b, __bf16* __restrict__ zr,
    int* __restrict__ myflag, int* __restrict__ zflag, int postval)
{
    const int tid = threadIdx.x, lane = tid & 63, w = tid >> 6;

    float a0 = 0.f, a1 = 0.f;
    if (tid < HD) a0 = ldf_sc(h2g + hblk(b, tid));
    if (tid + 512 < HD) a1 = ldf_sc(h2g + hblk(b, tid + 512));
    vm_wait0();
    __builtin_amdgcn_sched_barrier(0);
    if (tid < HD) h2s[tid] = a0;
    if (tid + 512 < HD) h2s[tid + 512] = a1;
    __syncthreads();
    if (tid == 0) sti_sc(myflag, postval);

    const float2* h22 = (const float2*)h2s;
    for (int t = w; t < TE; t += 8) {
        const float2* y2 = (const float2*)(yencL + t * HD);
        float p = 0.f;
#pragma unroll
        for (int it = 0; it < HD / 128; ++it) {
            const float2 ya = y2[lane + it * 64];
            const float2 hb2 = h22[lane + it * 64];
            p += ya.x * hb2.x + ya.y * hb2.y;
        }
        p += __shfl_down(p, 32); p += __shfl_down(p, 16); p += __shfl_down(p, 8);
        p += __shfl_down(p, 4);  p += __shfl_down(p, 2);  p += __shfl_down(p, 1);
        if (lane == 0) scL[t] = p;
    }
    __syncthreads();

    float m = scL[0];
    for (int t = 1; t < TE; ++t) m = fmaxf(m, scL[t]);
    float s = 0.f;
    for (int t = 0; t < TE; ++t) s += __expf(scL[t] - m);
    const float inv = 1.0f / s;
    if (tid < TE) attwL[tid] = __expf(scL[tid] - m) * inv;
    __syncthreads();

    for (int c = tid; c < HD; c += 512) {
        float acc = 0.f;
#pragma unroll
        for (int t = 0; t < TE; ++t) acc += attwL[t] * yencL[t * HD + c];
        sth_sc(zr + (size_t)b * KZ + HD + c, acc);
    }
    vm_wait0();
    __syncthreads();
    if (tid == 0) sti_sc(zflag, postval);
}

// ---------------------------------------------------------------------------
// Persistent kernel: recurrence roles (blocks 0..119) + fcW conversion (worker
// blocks 120..247 during encoder idle, FWC-gated) + FC tile queue. Softmax
// runs as a SEPARATE kernel after (r15/r16/r17 showed in-kernel softmax
// interferes with the L3-latency-bound decoder).
// ---------------------------------------------------------------------------
__global__ __launch_bounds__(512, 1) void recur(
    const float* __restrict__ GIf, const float* __restrict__ GIb,
    const float* __restrict__ GId,
    const float* __restrict__ WhhF, const float* __restrict__ WhhB,
    const float* __restrict__ WhhD,
    const float* __restrict__ bhhF, const float* __restrict__ bhhB,
    const float* __restrict__ bhhD,
    float* __restrict__ heF, __bf16* __restrict__ heB,
    float* __restrict__ hdF, __bf16* __restrict__ hdB,
    float* __restrict__ yenc_f, float* __restrict__ yenc_b,
    __bf16* __restrict__ Zb, int* __restrict__ flags,
    const float* __restrict__ fcWsrc, __bf16* __restrict__ fcW,
    float* __restrict__ outC, const float* __restrict__ fcb)
{
    __shared__ __align__(16) char smem[147456];
    __bf16* wlds  = (__bf16*)smem;
    float*  yencL = (float*)smem;
    float*  h2s   = (float*)(smem + 143360);
    float*  scL   = (float*)(smem + 146944);
    float*  attwL = (float*)(smem + 147136);
    volatile int* shtile = (volatile int*)(smem + 147400);

    const int gid = blockIdx.x;
    const int tid = threadIdx.x;
    const int lane = tid & 63, w = tid >> 6;
    const int r16 = lane & 15, hi = lane >> 4;
    const size_t S = (size_t)BB * HD;

    if (gid < NBLK) {
        float bb0 = 0.f, bb1 = 0.f, bb2 = 0.f;
        GiReg gi;

        // ================= encoder =================
        if (gid < 112) {
            const int dir = (gid >= 56) ? 1 : 0;
            const int gloc = dir ? gid - 56 : gid;
            const int c0e = gloc * 16;
            const float* GIe  = dir ? GIb : GIf;
            const float* bhhE = dir ? bhhB : bhhF;
            float* yencD = dir ? yenc_b : yenc_f;
            const int foff = dir ? BOFF : FOFF;
            const int ce = c0e + r16;

            stage_w(wlds, dir ? WhhB : WhhF, c0e);
            if (tid < 256) {
                bb0 = bhhE[ce]; bb1 = bhhE[HD + ce]; bb2 = bhhE[2 * HD + ce];
                gi = gi_prefetch(GIe + (size_t)(dir ? TE - 1 : 0) * BB * G3, ce, w, hi);
            }
            __syncthreads();

            for (int t = 0; t < TE; ++t) {
                if (t > 0) {
                    if (tid < 56) spin_ge(flags + (foff + tid) * FSTR, t);
                    __syncthreads();
                }
                const int tt = dir ? (TE - 1 - t) : t;
                if (tid < 256)
                    gru_step(heB + (size_t)(dir * 2 + (t & 1)) * S,
                             heF + (size_t)(dir * 2 + (t & 1)) * S,
                             wlds, gi, bb0, bb1, bb2,
                             heF + (size_t)(dir * 2 + ((t + 1) & 1)) * S,
                             heB + (size_t)(dir * 2 + ((t + 1) & 1)) * S,
                             yencD, tt, nullptr, c0e, lane, w);
                vm_wait0();
                __syncthreads();
                if (tid == 0) sti_sc(flags + (foff + gloc) * FSTR, t + 1);
                if (t + 1 < TE && tid < 256) {
                    const int ttn = dir ? (TE - 2 - t) : (t + 1);
                    gi = gi_prefetch(GIe + (size_t)ttn * BB * G3, ce, w, hi);
                }
            }
        }

        // ================= transition =================
        if (tid < 112) spin_ge(flags + tid * FSTR, TE);
        __syncthreads();

        {
            const int i0 = gid * 256 + tid;
            const int i1 = i0 + NBLK * 256;
            const bool has0 = (i0 < BB * HD);
            const bool has1 = (i1 < BB * HD);
            const float f0 = has0 ? ldf_sc(&heF[0 * S + i0]) : 0.f;
            const float b0 = has0 ? ldf_sc(&heF[2 * S + i0]) : 0.f;
            const float f1 = has1 ? ldf_sc(&heF[0 * S + i1]) : 0.f;
            const float b1 = has1 ? ldf_sc(&heF[2 * S + i1]) : 0.f;
            vm_wait0();
            __builtin_amdgcn_sched_barrier(0);
            if (has0) { const float v0 = f0 + b0; stf_sc(&hdF[i0], v0); sth_sc(&hdB[i0], v0); }
            if (has1) { const float v1 = f1 + b1; stf_sc(&hdF[i1], v1); sth_sc(&hdB[i1], v1); }
        }
        if (gid < 56) {
            stage_w(wlds, WhhD, gid * 16);
            if (tid < 256) {
                const int cd = gid * 16 + r16;
                bb0 = bhhD[cd]; bb1 = bhhD[HD + cd]; bb2 = bhhD[2 * HD + cd];
                gi = gi_prefetch(GId, cd, w, hi);
            }
        }
        vm_wait0();
        __syncthreads();
        if (tid == 0) sti_sc(flags + (TOFF + gid) * FSTR, 1);
        if (tid < 120) spin_ge(flags + (TOFF + tid) * FSTR, 1);
        __syncthreads();

        // ================= decoder =================
        if (gid < 56) {
            for (int p = 0; p < TD; ++p) {
                if (p > 0 && tid < 56) spin_ge(flags + (DOFF + tid) * FSTR, p);
                if (p >= 4 && tid >= 64 && tid < 128)
                    spin_ge(flags + (AOFF + tid - 64) * FSTR, p - 3);
                __syncthreads();
                if (tid < 256)
                    gru_step(hdB + (size_t)(p & 3) * S, hdF + (size_t)(p & 3) * S,
                             wlds, gi, bb0, bb1, bb2,
                             hdF + (size_t)((p + 1) & 3) * S, hdB + (size_t)((p + 1) & 3) * S,
                             nullptr, 0, Zb + (size_t)p * BB * KZ, gid * 16, lane, w);
                vm_wait0();
                __syncthreads();
                if (tid == 0) sti_sc(flags + (DOFF + gid) * FSTR, p + 1);
                if (p + 1 < TD && tid < 256)
                    gi = gi_prefetch(GId + (size_t)(p + 1) * BB * G3, gid * 16 + r16, w, hi);
            }
        } else {
            const int b = gid - 56;
            const float* sf = yenc_f;
            const float* sb = yenc_b;
            for (int it = 0; it < 4; ++it) {
                f32x4 a_[5], b_[5];
                int tt_[5], gg_[5], cc_[5]; bool ok[5];
#pragma unroll
                for (int u = 0; u < 5; ++u) {
                    const int j = it * 2560 + u * 512 + tid;
                    ok[u] = (j < 8960);
                    if (ok[u]) {
                        gg_[u] = j / 160;
                        const int rem = j - gg_[u] * 160;
                        tt_[u] = rem >> 2;
                        cc_[u] = (rem & 3) * 4;
                        const size_t sa = (((size_t)gg_[u] * 64 + b) * TE + tt_[u]) * 16 + cc_[u];
                        a_[u] = ldf4_sc(sf + sa);
                        b_[u] = ldf4_sc(sb + sa);
                    }
                }
                vm_wait0();
                __builtin_amdgcn_sched_barrier(0);
#pragma unroll
                for (int u = 0; u < 5; ++u)
                    if (ok[u])
                        *(f32x4*)&yencL[(size_t)tt_[u] * HD + gg_[u] * 16 + cc_[u]] = a_[u] + b_[u];
            }
            __syncthreads();
            for (int s = 0; s < TD; ++s) {
                if (tid < 56) spin_ge(flags + (DOFF + tid) * FSTR, s + 1);
                __syncthreads();
                attn_step512(yencL, h2s, scL, attwL, hdF + (size_t)((s + 1) & 3) * S,
                             b, Zb + (size_t)s * BB * KZ,
                             flags + (AOFF + b) * FSTR, flags + (ZOFF + b) * FSTR, s + 1);
            }
        }
    } else {
        // ============ worker blocks: convert fcW fp32->bf16 (sc1) ============
        const int slice = gid - NBLK;                    // 0..127
        const size_t base = (size_t)slice * 236 * KZ;    // 236 rows per slice
        const int nf4 = 236 * KZ / 4;
        for (int i = tid; i < nf4; i += 512) {
            const size_t e0 = base + (size_t)i * 4;
            const int r = (int)(e0 / KZ);
            u16x4 o;
            if (r < VO) {
                const float4 x = *(const float4*)&fcWsrc[e0];
                o.x = __builtin_bit_cast(unsigned short, (__bf16)x.x);
                o.y = __builtin_bit_cast(unsigned short, (__bf16)x.y);
                o.z = __builtin_bit_cast(unsigned short, (__bf16)x.z);
                o.w = __builtin_bit_cast(unsigned short, (__bf16)x.w);
            } else {
                o.x = 0; o.y = 0; o.z = 0; o.w = 0;
            }
            st8_sc(&fcW[e0], o);
        }
        vm_wait0();
        __syncthreads();
        if (tid == 0)
            __hip_atomic_fetch_add(flags + FWC * FSTR, 1, __ATOMIC_RELAXED,
                                   __HIP_MEMORY_SCOPE_AGENT);
    }

    // ================= FC phase (all blocks) =================
    {
        __bf16* lds = (__bf16*)smem;
        const int wave = tid >> 6;
        const int wm = wave >> 2, wn = wave & 3;
        int* qcnt = flags + QOFF * FSTR;

        if (tid == 0) spinb(flags + FWC * FSTR, 128);   // fcW conversion done
        __syncthreads();

        const int srow0 = wave * 8 + (lane >> 3);
        const int scol  = ((lane & 7) ^ (lane >> 3)) * 8;
        const int cbx0 = ((hi * 16) ^ ((r16 & 7) << 4)) >> 1;
        const int cbx1 = ((64 + hi * 16) ^ ((r16 & 7) << 4)) >> 1;

        for (;;) {
            if (tid == 0) {
                const int tl = __hip_atomic_fetch_add(qcnt, 1, __ATOMIC_RELAXED,
                                                      __HIP_MEMORY_SCOPE_AGENT);
                *shtile = tl;
            }
            __syncthreads();
            const int tile = *shtile;
            if (tile >= NTILE) break;
            const int mt = tile / NTN, nt = tile - mt * NTN;
            const int need = 4 * mt + 4;
            if (tid < 56) spinb(flags + (DOFF + tid) * FSTR, need);
            if (tid >= 64 && tid < 128) spinb(flags + (ZOFF + tid - 64) * FSTR, need);
            __syncthreads();

            const long tileM = (long)mt * 256;
            const long tileN = (long)nt * 256;
            const __bf16* gAh[2] = { Zb + (size_t)tileM * KZ, Zb + (size_t)(tileM + 128) * KZ };
            const __bf16* gBh[2] = { fcW + (size_t)tileN * KZ, fcW + (size_t)(tileN + 128) * KZ };
            auto Abase = [](int buf, int h) { return (buf * 2 + h) * 8192; };
            auto Bbase = [](int buf, int h) { return 32768 + (buf * 2 + h) * 8192; };
            auto stageA = [&](const __bf16* gph, int kt, int lbase) {
                const __bf16* g0 = gph + (size_t)srow0 * KZ + kt * 64 + scol;
                gload_lds16_sc(g0, &lds[lbase + wave * 512]);
                gload_lds16_sc(g0 + (size_t)64 * KZ, &lds[lbase + (8 + wave) * 512]);
            };
            auto stageB = [&](const __bf16* gph, int kt, int lbase) {
                const __bf16* g0 = gph + (size_t)srow0 * KZ + kt * 64 + scol;
                gload_lds16(g0, &lds[lbase + wave * 512]);
                gload_lds16(g0 + (size_t)64 * KZ, &lds[lbase + (8 + wave) * 512]);
            };

            f32x4 acc[8][4];
            const f32x4 zero = {0.f, 0.f, 0.f, 0.f};
#pragma unroll
            for (int m = 0; m < 8; ++m)
#pragma unroll
                for (int n = 0; n < 4; ++n) acc[m][n] = zero;

            stageA(gAh[0], 0, Abase(0, 0));
            stageA(gAh[1], 0, Abase(0, 1));
            stageB(gBh[0], 0, Bbase(0, 0));
            stageB(gBh[1], 0, Bbase(0, 1));
            stageB(gBh[0], 1, Bbase(1, 0));
            stageB(gBh[1], 1, Bbase(1, 1));
            asm volatile("s_waitcnt vmcnt(4)" ::: "memory");
            __builtin_amdgcn_s_barrier();

            for (int kt = 0; kt < KT; ++kt) {
                const int buf = kt & 1;
                const int kn1 = (kt + 1 < KT) ? kt + 1 : 0;
                const int kn2 = (kt + 2 < KT) ? kt + 2 : 0;
                const int Ab = Abase(buf, wm);
                const int Bb = Bbase(buf, wn >> 1);
                bf16x8 bfr[4][2];
#pragma unroll
                for (int q = 0; q < 4; ++q) {
                    if (q == 0) {
#pragma unroll
                        for (int n = 0; n < 4; ++n) {
                            const int rowB = (wn & 1) * 64 + n * 16 + r16;
                            bfr[n][0] = *(const bf16x8*)&lds[Bb + rowB * 64 + cbx0];
                            bfr[n][1] = *(const bf16x8*)&lds[Bb + rowB * 64 + cbx1];
                        }
                    }
                    bf16x8 af[2][2];
#pragma unroll
                    for (int mm = 0; mm < 2; ++mm) {
                        const int rowA = (q * 2 + mm) * 16 + r16;
                        af[mm][0] = *(const bf16x8*)&lds[Ab + rowA * 64 + cbx0];
                        af[mm][1] = *(const bf16x8*)&lds[Ab + rowA * 64 + cbx1];
                    }
                    if (q == 0)      stageA(gAh[0], kn1, Abase(buf ^ 1, 0));
                    else if (q == 1) stageA(gAh[1], kn1, Abase(buf ^ 1, 1));
                    else if (q == 2) stageB(gBh[0], kn2, Bbase(buf, 0));
                    else {
                        stageB(gBh[1], kn2, Bbase(buf, 1));
                        asm volatile("s_waitcnt vmcnt(4)" ::: "memory");
                    }
                    __builtin_amdgcn_s_barrier();
                    asm volatile("s_waitcnt lgkmcnt(0)" ::: "memory");
                    __builtin_amdgcn_sched_barrier(0);
                    __builtin_amdgcn_s_setprio(1);
#pragma unroll
                    for (int mm = 0; mm < 2; ++mm)
#pragma unroll
                        for (int n = 0; n < 4; ++n) {
                            acc[q * 2 + mm][n] = __builtin_amdgcn_mfma_f32_16x16x32_bf16(
                                af[mm][0], bfr[n][0], acc[q * 2 + mm][n], 0, 0, 0);
                            acc[q * 2 + mm][n] = __builtin_amdgcn_mfma_f32_16x16x32_bf16(
                                af[mm][1], bfr[n][1], acc[q * 2 + mm][n], 0, 0, 0);
                        }
                    __builtin_amdgcn_s_setprio(0);
                    __builtin_amdgcn_sched_barrier(0);
                    __builtin_amdgcn_s_barrier();
                }
            }
            asm volatile("s_waitcnt vmcnt(0)" ::: "memory");

            // epilogue: plain stores (consumer is the post-kernel softmax)
#pragma unroll
            for (int m = 0; m < 8; ++m) {
#pragma unroll
                for (int n = 0; n < 4; ++n) {
                    const long gcol = tileN + wn * 64 + n * 16 + r16;
                    if (gcol >= VO) continue;
                    const float bv = fcb[gcol];
#pragma unroll
                    for (int rr = 0; rr < 4; ++rr) {
                        const long grow = tileM + wm * 128 + m * 16 + hi * 4 + rr;
                        const long t = grow >> 6, b = grow & 63;
                        outC[(b * TD + t) * VO + gcol] = acc[m][n][rr] + bv;
                    }
                }
            }
            __syncthreads();
        }
    }
}

// ---------------------------------------------------------------------------
// 128^2 T3+T4 GEMM (proven): input-side GEMMs. fp32 C.
// ---------------------------------------------------------------------------
__global__ __launch_bounds__(256) void gemm_bt(
    const __bf16* __restrict__ A0, const __bf16* __restrict__ B0,
    float* __restrict__ C0, const float* __restrict__ bias0,
    const __bf16* __restrict__ A1, const __bf16* __restrict__ B1,
    float* __restrict__ C1, const float* __restrict__ bias1,
    int M, int N, int K)
{
    constexpr int BM = 128, BN = 128, BK = 32;
    constexpr int FM = 4, FN = 4;

    const __bf16* A = A0; const __bf16* Bp = B0;
    float* C = C0; const float* bias = bias0;
    if (blockIdx.z == 1) { A = A1; Bp = B1; C = C1; bias = bias1; }

    __shared__ __bf16 Ash[2][BM * BK];
    __shared__ __bf16 Bsh[2][BN * BK];

    const int tid  = threadIdx.x;
    const int lane = tid & 63;
    const int wave = tid >> 6;
    const int wr = wave >> 1, wc = wave & 1;

    const int nwg = gridDim.x * gridDim.y;
    const int orig = blockIdx.y * gridDim.x + blockIdx.x;
    const int q = nwg >> 3, r = nwg & 7;
    const int xcd = orig & 7, idx = orig >> 3;
    const int wg = (xcd < r ? xcd * (q + 1) : r * (q + 1) + (xcd - r) * q) + idx;
    const int mtiles = gridDim.y;
    const long tileM = (long)(wg % mtiles) * BM;
    const long tileN = (long)(wg / mtiles) * BN;

    const int r16 = lane & 15;
    const int hi  = lane >> 4;

    f32x4 acc[FM][FN];
    const f32x4 zero = {0.f, 0.f, 0.f, 0.f};
#pragma unroll
    for (int m = 0; m < FM; ++m)
#pragma unroll
        for (int n = 0; n < FN; ++n) acc[m][n] = zero;

    const int srow = wave * 32 + (lane >> 2);
    const int schunk = (lane & 3) * 8;
    const __bf16* gA = A + (size_t)(tileM + srow) * K + schunk;
    const __bf16* gB = Bp + (size_t)(tileN + srow) * K + schunk;
    const size_t kstep16 = (size_t)16 * K;
    const int lofs = (wave * 32) * BK;

#define STAGE_T(k0_, sel_)                                            \
    do {                                                              \
        gload_lds16(gA + (k0_), &Ash[sel_][lofs]);                    \
        gload_lds16(gA + (k0_) + kstep16, &Ash[sel_][lofs + 16 * BK]);\
        gload_lds16(gB + (k0_), &Bsh[sel_][lofs]);                    \
        gload_lds16(gB + (k0_) + kstep16, &Bsh[sel_][lofs + 16 * BK]);\
    } while (0)

    STAGE_T(0, 0);
    int cur = 0;
    for (int k0 = BK; k0 < K; k0 += BK) {
        STAGE_T(k0, cur ^ 1);
        asm volatile("s_waitcnt vmcnt(4)" ::: "memory");
        __builtin_amdgcn_s_barrier();
        __builtin_amdgcn_sched_barrier(0);

        bf16x8 af[FM], bfr[FN];
#pragma unroll
        for (int m = 0; m < FM; ++m)
            af[m] = *(const bf16x8*)&Ash[cur][(wr * 64 + m * 16 + r16) * BK + hi * 8];
#pragma unroll
        for (int n = 0; n < FN; ++n)
            bfr[n] = *(const bf16x8*)&Bsh[cur][(wc * 64 + n * 16 + r16) * BK + hi * 8];
#pragma unroll
        for (int m = 0; m < FM; ++m)
#pragma unroll
            for (int n = 0; n < FN; ++n)
                acc[m][n] = __builtin_amdgcn_mfma_f32_16x16x32_bf16(af[m], bfr[n], acc[m][n], 0, 0, 0);

        __builtin_amdgcn_sched_barrier(0);
        __builtin_amdgcn_s_barrier();
        __builtin_amdgcn_sched_barrier(0);
        cur ^= 1;
    }
    asm volatile("s_waitcnt vmcnt(0)" ::: "memory");
    __builtin_amdgcn_s_barrier();
    __builtin_amdgcn_sched_barrier(0);
    {
        bf16x8 af[FM], bfr[FN];
#pragma unroll
        for (int m = 0; m < FM; ++m)
            af[m] = *(const bf16x8*)&Ash[cur][(wr * 64 + m * 16 + r16) * BK + hi * 8];
#pragma unroll
        for (int n = 0; n < FN; ++n)
            bfr[n] = *(const bf16x8*)&Bsh[cur][(wc * 64 + n * 16 + r16) * BK + hi * 8];
#pragma unroll
        for (int m = 0; m < FM; ++m)
#pragma unroll
            for (int n = 0; n < FN; ++n)
                acc[m][n] = __builtin_amdgcn_mfma_f32_16x16x32_bf16(af[m], bfr[n], acc[m][n], 0, 0, 0);
    }
#undef STAGE_T

#pragma unroll
    for (int m = 0; m < FM; ++m) {
#pragma unroll
        for (int n = 0; n < FN; ++n) {
            const long gcol = tileN + wc * 64 + n * 16 + r16;
            const float bv = bias ? bias[gcol] : 0.0f;
#pragma unroll
            for (int rr = 0; rr < 4; ++rr) {
                const long grow = tileM + wr * 64 + m * 16 + hi * 4 + rr;
                C[grow * N + gcol] = acc[m][n][rr] + bv;
            }
        }
    }
}

// fp32 -> bf16 convert with row/col zero-padding (small Wih matrices)
__global__ __launch_bounds__(256) void conv_pad(const float* __restrict__ src,
                                                __bf16* __restrict__ dst,
                                                int Rout, int Rin, int Kout, int Kin)
{
    size_t i = (size_t)blockIdx.x * 256 + threadIdx.x;
    const size_t total = (size_t)Rout * Kout;
    const size_t stride = (size_t)gridDim.x * 256;
    for (; i < total; i += stride) {
        int k = (int)(i % Kout);
        int r = (int)(i / Kout);
        float v = (r < Rin && k < Kin) ? src[(size_t)r * Kin + k] : 0.0f;
        dst[i] = (__bf16)v;
    }
}

// gather token embeddings into padded bf16 matrix X[(t*B+b)][EP]
__global__ __launch_bounds__(256) void gather_embed(const int* __restrict__ tok,
                                                    const float* __restrict__ emb,
                                                    __bf16* __restrict__ X)
{
    int i = blockIdx.x * 256 + threadIdx.x;
    const int total = TE * BB * EP;
    for (; i < total; i += gridDim.x * 256) {
        int e = i % EP;
        int row = i / EP;
        int t = row >> 6, b = row & 63;
        float v = 0.0f;
        if (e < ED) v = emb[(size_t)tok[b * TE + t] * ED + e];
        X[i] = (__bf16)v;
    }
}

// LDS-staged row softmax, single-exp, 1024 threads (r14-proven standalone)
__global__ __launch_bounds__(1024) void softmax_kernel(float* __restrict__ out)
{
    __shared__ float row[VO];
    __shared__ float red[16];
    __shared__ float red2[16];
    const size_t base = (size_t)blockIdx.x * VO;
    const int tid = threadIdx.x;
    const int lane = tid & 63, w = tid >> 6;

    float m = -1e30f;
    for (int ch = tid; ch < VO / 4; ch += 1024) {
        const float4 x = *(const float4*)&out[base + ch * 4];
        *(float4*)&row[ch * 4] = x;
        m = fmaxf(fmaxf(fmaxf(m, x.x), x.y), fmaxf(x.z, x.w));
    }
    m = fmaxf(m, __shfl_down(m, 32)); m = fmaxf(m, __shfl_down(m, 16));
    m = fmaxf(m, __shfl_down(m, 8));  m = fmaxf(m, __shfl_down(m, 4));
    m = fmaxf(m, __shfl_down(m, 2));  m = fmaxf(m, __shfl_down(m, 1));
    if (lane == 0) red[w] = m;
    __syncthreads();
    if (tid == 0) {
        float mm = red[0];
#pragma unroll
        for (int i = 1; i < 16; ++i) mm = fmaxf(mm, red[i]);
        red[0] = mm;
    }
    __syncthreads();
    m = red[0];

    float s = 0.0f;
    for (int v = tid; v < VO; v += 1024) {
        const float e = __expf(row[v] - m);
        row[v] = e;
        s += e;
    }
    s += __shfl_down(s, 32); s += __shfl_down(s, 16); s += __shfl_down(s, 8);
    s += __shfl_down(s, 4);  s += __shfl_down(s, 2);  s += __shfl_down(s, 1);
    if (lane == 0) red2[w] = s;
    __syncthreads();
    if (tid == 0) {
        float ss = red2[0];
#pragma unroll
        for (int i = 1; i < 16; ++i) ss += red2[i];
        red2[0] = ss;
    }
    __syncthreads();
    s = red2[0];

    const float inv = 1.0f / s;
    for (int ch = tid; ch < VO / 4; ch += 1024) {
        float4 x = *(const float4*)&row[ch * 4];
        x.x *= inv; x.y *= inv; x.z *= inv; x.w *= inv;
        *(float4*)&out[base + ch * 4] = x;
    }
}

extern "C" void kernel_launch(void* const* d_in, const int* in_sizes, int n_in,
                              void* d_out, int out_size, void* d_ws, size_t ws_size,
                              hipStream_t stream)
{
    if (n_in < 18) return;
    const int*   x_enc   = (const int*)d_in[0];
    const int*   x_dec   = (const int*)d_in[1];
    const float* emb_enc = (const float*)d_in[2];
    const float* Wih_f   = (const float*)d_in[3];
    const float* Whh_f   = (const float*)d_in[4];
    const float* bih_f   = (const float*)d_in[5];
    const float* bhh_f   = (const float*)d_in[6];
    const float* Wih_b   = (const float*)d_in[7];
    const float* Whh_b   = (const float*)d_in[8];
    const float* bih_b   = (const float*)d_in[9];
    const float* bhh_b   = (const float*)d_in[10];
    const float* emb_dec = (const float*)d_in[11];
    const float* Wih_d   = (const float*)d_in[12];
    const float* Whh_d   = (const float*)d_in[13];
    const float* bih_d   = (const float*)d_in[14];
    const float* bhh_d   = (const float*)d_in[15];
    const float* fc_W    = (const float*)d_in[16];
    const float* fc_b    = (const float*)d_in[17];
    float* out = (float*)d_out;

    size_t off = 0;
    auto alloc = [&](size_t bytes) -> void* {
        void* p = (char*)d_ws + off;
        off = (off + bytes + 255) & ~(size_t)255;
        return p;
    };
    __bf16* fcWb   = (__bf16*)alloc((size_t)VP2 * KZ * 2);
    __bf16* WihFb  = (__bf16*)alloc((size_t)G3 * EP * 2);
    __bf16* WihBb  = (__bf16*)alloc((size_t)G3 * EP * 2);
    __bf16* WihDb  = (__bf16*)alloc((size_t)G3 * EP * 2);
    __bf16* Xe     = (__bf16*)alloc((size_t)MR * EP * 2);
    __bf16* Xd     = (__bf16*)alloc((size_t)MR * EP * 2);
    float*  GIf    = (float*)alloc((size_t)MR * G3 * 4);
    float*  GIb    = (float*)alloc((size_t)MR * G3 * 4);
    float*  GId    = (float*)alloc((size_t)MR * G3 * 4);
    __bf16* Zb     = (__bf16*)alloc((size_t)MR * KZ * 2);
    float*  yenc_f = (float*)alloc((size_t)BB * TE * HD * 4);
    float*  yenc_b = (float*)alloc((size_t)BB * TE * HD * 4);
    float*  hdF    = (float*)alloc((size_t)4 * BB * HD * 4);
    __bf16* hdB    = (__bf16*)alloc((size_t)4 * BB * HD * 2);
    char* zero_start = (char*)d_ws + off;
    float*  heF    = (float*)alloc((size_t)4 * BB * HD * 4);
    __bf16* heB    = (__bf16*)alloc((size_t)4 * BB * HD * 2);
    int*    flags  = (int*)alloc(512 * FSTR * 4);
    size_t zero_bytes = (size_t)(((char*)d_ws + off) - zero_start);
    if (off > ws_size) return;   // ~230 MB required; fail visibly (zero output)

    // ---- init + small weight conversion + embedding gather ----
    hipMemsetAsync(zero_start, 0, zero_bytes, stream);
    conv_pad<<<3360, 256, 0, stream>>>(Wih_f, WihFb, G3, G3, EP, ED);
    conv_pad<<<3360, 256, 0, stream>>>(Wih_b, WihBb, G3, G3, EP, ED);
    conv_pad<<<3360, 256, 0, stream>>>(Wih_d, WihDb, G3, G3, EP, ED);
    gather_embed<<<3200, 256, 0, stream>>>(x_enc, emb_enc, Xe);
    gather_embed<<<3200, 256, 0, stream>>>(x_dec, emb_dec, Xd);

    // ---- batched input-side GEMMs: GI = X @ Wih^T + bih ----
    gemm_bt<<<dim3(G3 / 128, MR / 128, 2), 256, 0, stream>>>(
        Xe, WihFb, GIf, bih_f, Xe, WihBb, GIb, bih_b, MR, G3, EP);
    gemm_bt<<<dim3(G3 / 128, MR / 128, 1), 256, 0, stream>>>(
        Xd, WihDb, GId, bih_d, nullptr, nullptr, nullptr, nullptr, MR, G3, EP);

    // ---- persistent: recurrence + fcW conversion + FC (one kernel) ----
    recur<<<NWB, 512, 0, stream>>>(GIf, GIb, GId, Whh_f, Whh_b, Whh_d,
                                   bhh_f, bhh_b, bhh_d,
                                   heF, heB, hdF, hdB, yenc_f, yenc_b, Zb, flags,
                                   fc_W, fcWb, out, fc_b);

    // ---- standalone softmax (plain loads; kernel-boundary coherence) ----
    softmax_kernel<<<BB * TD, 1024, 0, stream>>>(out);
}